// Round 1
// baseline (1750.156 us; speedup 1.0000x reference)
//
#include <hip/hip_runtime.h>
#include <hip/hip_fp16.h>
#include <math.h>

// ---------------- problem constants ----------------
static constexpr int   B_    = 4;
static constexpr int   N_    = 4096;
static constexpr int   BOX_  = 128;
static constexpr long long VOX_ = 1LL * BOX_ * BOX_ * BOX_;   // 2097152
static constexpr float EPS_IN_C  = 6.5f;
static constexpr float EPS_OUT_C = 79.0f;
static constexpr float QCONV_C   = 7046.52f;
static constexpr float KAPPA02_C = 0.8486f;
static constexpr float FOURPI_C  = 12.566370614359172f;

// ---------------- trilinear charge scatter (verified) ----------
__global__ void scatter_q_kernel(const float* __restrict__ coords,
                                 const float* __restrict__ params,
                                 const int*   __restrict__ num_atoms,
                                 float* __restrict__ q)
{
    int a = blockIdx.x * blockDim.x + threadIdx.x;
    if (a >= B_ * N_) return;
    int b = a >> 12;
    int n = a & (N_ - 1);
    if (n >= num_atoms[b]) return;

    float cx = coords[3 * a + 0];
    float cy = coords[3 * a + 1];
    float cz = coords[3 * a + 2];
    float chg = params[2 * a + 0] * QCONV_C;

    int ix0 = (int)floorf(cx), iy0 = (int)floorf(cy), iz0 = (int)floorf(cz);
    float fx = cx - (float)ix0, fy = cy - (float)iy0, fz = cz - (float)iz0;
    float wx[2] = {1.0f - fx, fx};
    float wy[2] = {1.0f - fy, fy};
    float wz[2] = {1.0f - fz, fz};

    float* qb = q + (long long)b * VOX_;
#pragma unroll
    for (int dx = 0; dx < 2; ++dx) {
        int ix = ix0 + dx;
        if ((unsigned)ix >= 128u) continue;
#pragma unroll
        for (int dy = 0; dy < 2; ++dy) {
            int iy = iy0 + dy;
            if ((unsigned)iy >= 128u) continue;
#pragma unroll
            for (int dz = 0; dz < 2; ++dz) {
                int iz = iz0 + dz;
                if ((unsigned)iz >= 128u) continue;
                atomicAdd(&qb[((long long)ix * 128 + iy) * 128 + iz],
                          chg * wx[dx] * wy[dy] * wz[dz]);
            }
        }
    }
}

// ---------------- eps gather v2: separable per-axis weights in LDS ----------
// Weight semantics identical to verified round-5 axis_d2 (JAX wrap on negatives).
#define CAND_CAP 512
#define CHUNK 32

__global__ void eps_gather_v2(const float* __restrict__ coords,
                              const float* __restrict__ params,
                              const int*   __restrict__ num_atoms,
                              float* __restrict__ eps)   // [B][4][128^3]
{
    int tileId = blockIdx.x;            // B * 4096 tiles
    int b  = tileId >> 12;
    int t  = tileId & 4095;
    int tx = ((t >> 8) & 15) << 3;
    int ty = ((t >> 4) & 15) << 3;
    int tz = (t & 15) << 3;

    __shared__ float sx[CAND_CAP], sy[CAND_CAP], sz[CAND_CAP], sr[CAND_CAP];
    __shared__ float wts[CHUNK][9][8];   // [atom][axis*3+variant][tile pos]
    __shared__ int s_cnt;
    if (threadIdx.x == 0) s_cnt = 0;
    __syncthreads();

    int na = num_atoms[b];
    const float* cb = coords + (size_t)b * N_ * 3;
    const float* pb = params + (size_t)b * N_ * 2;

    float lox = (float)tx - 6.0f, hix = (float)tx + 14.0f;
    float loy = (float)ty - 6.0f, hiy = (float)ty + 14.0f;
    float loz = (float)tz - 6.0f, hiz = (float)tz + 14.0f;
    bool wx_ = (tx == 120), wy_ = (ty == 120), wz_ = (tz == 120);
    for (int n = threadIdx.x; n < na; n += blockDim.x) {
        float cx = cb[3 * n], cy = cb[3 * n + 1], cz = cb[3 * n + 2];
        bool okx = (cx >= lox && cx < hix) || (wx_ && cx < 6.0f);
        bool oky = (cy >= loy && cy < hiy) || (wy_ && cy < 6.0f);
        bool okz = (cz >= loz && cz < hiz) || (wz_ && cz < 6.0f);
        if (okx && oky && okz) {
            int slot = atomicAdd(&s_cnt, 1);
            if (slot < CAND_CAP) {
                sx[slot] = cx; sy[slot] = cy; sz[slot] = cz;
                sr[slot] = pb[2 * n + 1];
            }
        }
    }
    __syncthreads();
    int cnt = min(s_cnt, CAND_CAP);

    int lz = threadIdx.x & 7;
    int ly = (threadIdx.x >> 3) & 7;
    int lx = threadIdx.x >> 6;

    float r0 = 0.0f, r1 = 0.0f, r2 = 0.0f, r3 = 0.0f;

    for (int k0 = 0; k0 < cnt; k0 += CHUNK) {
        int nC = min(CHUNK, cnt - k0);
        __syncthreads();   // protect wts reuse across chunk iterations
        // Phase A: fill per-atom separable axis weights (72 expf per atom)
        for (int w = threadIdx.x; w < nC * 72; w += 512) {
            int ka  = w / 72;
            int rem = w - ka * 72;
            int vi  = rem >> 3;        // 0..8 = axis*3 + variant
            int pos = rem & 7;
            int axis = vi / 3, var = vi - axis * 3;
            int k = k0 + ka;
            float c     = (axis == 0) ? sx[k] : (axis == 1) ? sy[k] : sz[k];
            int   torig = (axis == 0) ? tx    : (axis == 1) ? ty    : tz;
            float r = sr[k];
            float sig = (var == 2) ? (r + 1.0f) * 0.5f : (r + 1.4f) * 0.5f;
            float off = (var == 0) ? 0.0f : 0.5f;
            float inv2s2 = 1.0f / (2.0f * sig * sig);
            int i = torig + pos;
            int base = (int)floorf(c - off) - 4;    // window [base, base+8]
            float wv = 0.0f;
            if ((unsigned)(i - base) <= 8u) {
                float d = (float)i + off - c;
                wv = expf(-d * d * inv2s2);
            } else if ((unsigned)(i - 128 - base) <= 8u) {   // JAX negative wrap
                float d = (float)(i - 128) + off - c;
                wv = expf(-d * d * inv2s2);
            }
            wts[ka][vi][pos] = wv;
        }
        __syncthreads();
        // Phase B: accumulate channels from separable products
        for (int ka = 0; ka < nC; ++ka) {
            float xE0 = wts[ka][0][lx], xE5 = wts[ka][1][lx], xI5 = wts[ka][2][lx];
            float yE0 = wts[ka][3][ly], yE5 = wts[ka][4][ly], yI5 = wts[ka][5][ly];
            float zE0 = wts[ka][6][lz], zE5 = wts[ka][7][lz], zI5 = wts[ka][8][lz];
            r0 += xE5 * yE0 * zE0;     // c0: off (.5,0,0)  sigE
            r1 += xE0 * yE5 * zE0;     // c1: off (0,.5,0)  sigE
            r2 += xE0 * yE0 * zE5;     // c2: off (0,0,.5)  sigE
            r3 += xI5 * yI5 * zI5;     // c3: off (.5,.5,.5) sigI
        }
    }

    int ix = tx + lx, iy = ty + ly, iz = tz + lz;
    size_t sp = ((size_t)ix * 128 + iy) * 128 + iz;
    float* eb = eps + (size_t)b * 4 * VOX_;
    eb[sp]                    = EPS_OUT_C + (EPS_IN_C - EPS_OUT_C) * fminf(fmaxf(r0, 0.0f), 1.0f);
    eb[sp + (size_t)VOX_]     = EPS_OUT_C + (EPS_IN_C - EPS_OUT_C) * fminf(fmaxf(r1, 0.0f), 1.0f);
    eb[sp + (size_t)VOX_ * 2] = EPS_OUT_C + (EPS_IN_C - EPS_OUT_C) * fminf(fmaxf(r2, 0.0f), 1.0f);
    eb[sp + (size_t)VOX_ * 3] = EPS_OUT_C + (EPS_IN_C - EPS_OUT_C) * fminf(fmaxf(r3, 0.0f), 1.0f);
}

// ---------------- coefficient pack v2: 8B faces + 4B fp32 rcp per voxel -----
// F[g] = {half2(ex, ey), half2(ez, 4*pi*q*rcp)}   (each value fp16-rounded ONCE)
// R[g] = 1/denom as fp32 (no extra rounding vs previous scheme)
__global__ void coef_pack2(const float* __restrict__ eps,
                           const float* __restrict__ q,
                           uint2* __restrict__ F,
                           float* __restrict__ R)
{
    int bxy = blockIdx.x;
    int b = bxy >> 14;
    int x = (bxy >> 7) & 127;
    int y = bxy & 127;
    int z = threadIdx.x;

    size_t sp = ((size_t)x * 128 + y) * 128 + z;
    size_t g  = (size_t)b * (size_t)VOX_ + sp;
    const float* E = eps + (size_t)b * 4 * (size_t)VOX_;

    float ex = E[sp];
    float ey = E[sp + (size_t)VOX_];
    float ez = E[sp + (size_t)VOX_ * 2];
    float ek = E[sp + (size_t)VOX_ * 3];
    float exm = (x > 0) ? E[sp - 16384]                 : EPS_OUT_C;
    float eym = (y > 0) ? E[sp + (size_t)VOX_ - 128]    : EPS_OUT_C;
    float ezm = (z > 0) ? E[sp + (size_t)VOX_ * 2 - 1]  : EPS_OUT_C;

    float lam = (ek - EPS_IN_C) / (EPS_OUT_C - EPS_IN_C);
    lam = fminf(fmaxf(lam, 0.0f), 1.0f);
    float denom = ex + exm + ey + eym + ez + ezm + KAPPA02_C * lam;
    float rcp = 1.0f / denom;

    __half2 a = __floats2half2_rn(ex, ey);
    __half2 c = __floats2half2_rn(ez, FOURPI_C * q[g] * rcp);
    uint2 u;
    u.x = *(unsigned int*)&a;
    u.y = *(unsigned int*)&c;
    F[g] = u;
    R[g] = rcp;
}

// ---------------- Jacobi sweep v4: gather minus-faces from neighbors --------
// out = rcp * (ex*pxp + ex(x-1)*pxm + ey*pyp + ey(y-1)*pym + ez*pzp + ez(z-1)*pzm) + src'
// 20 B/voxel unique HBM traffic vs v3's 24 B (coef 16B -> 12B).
__device__ __forceinline__ float h_lo(unsigned int u) {
    __half2 h = *(__half2*)&u; return __low2float(h);
}
__device__ __forceinline__ float h_hi(unsigned int u) {
    __half2 h = *(__half2*)&u; return __high2float(h);
}

__global__ void jacobi_v4(const uint2* __restrict__ F,
                          const float* __restrict__ R,
                          const float* __restrict__ pin,
                          float* __restrict__ pout)
{
    int tid = blockIdx.x * blockDim.x + threadIdx.x;   // 0 .. B*VOX/4-1
    size_t g4 = (size_t)tid * 4;
    int z4 = (int)(g4 & 127);          // 0,4,...,124
    int y  = (int)((g4 >> 7) & 127);
    int x  = (int)((g4 >> 14) & 127);

    // ---- phi loads (identical pattern to verified v3) ----
    float4 pcv = *reinterpret_cast<const float4*>(pin + g4);
    float4 z4v = make_float4(0.f, 0.f, 0.f, 0.f);
    float4 pxpv = (x < 127) ? *reinterpret_cast<const float4*>(pin + g4 + 16384) : z4v;
    float4 pxmv = (x > 0)   ? *reinterpret_cast<const float4*>(pin + g4 - 16384) : z4v;
    float4 pypv = (y < 127) ? *reinterpret_cast<const float4*>(pin + g4 + 128)   : z4v;
    float4 pymv = (y > 0)   ? *reinterpret_cast<const float4*>(pin + g4 - 128)   : z4v;
    float zpE = (z4 < 124) ? pin[g4 + 4] : 0.0f;
    float zmE = (z4 > 0)   ? pin[g4 - 1] : 0.0f;

    float pxp[4] = {pxpv.x, pxpv.y, pxpv.z, pxpv.w};
    float pxm[4] = {pxmv.x, pxmv.y, pxmv.z, pxmv.w};
    float pyp[4] = {pypv.x, pypv.y, pypv.z, pypv.w};
    float pym[4] = {pymv.x, pymv.y, pymv.z, pymv.w};
    float pzp[4] = {pcv.y, pcv.z, pcv.w, zpE};
    float pzm[4] = {zmE, pcv.x, pcv.y, pcv.z};

    // ---- face/coef loads ----
    const uint4* Fc = reinterpret_cast<const uint4*>(F + g4);   // 2 voxels per uint4
    uint4 f01 = Fc[0];
    uint4 f23 = Fc[1];
    uint4 zu4 = make_uint4(0u, 0u, 0u, 0u);
    uint4 xm01 = zu4, xm23 = zu4, ym01 = zu4, ym23 = zu4;
    if (x > 0) {
        const uint4* p = reinterpret_cast<const uint4*>(F + g4 - 16384);
        xm01 = p[0]; xm23 = p[1];
    }
    if (y > 0) {
        const uint4* p = reinterpret_cast<const uint4*>(F + g4 - 128);
        ym01 = p[0]; ym23 = p[1];
    }
    uint2 zmF = make_uint2(0u, 0u);
    if (z4 > 0) zmF = F[g4 - 1];

    float4 rv = *reinterpret_cast<const float4*>(R + g4);

    unsigned int wA[4] = {f01.x, f01.z, f23.x, f23.z};   // {ex, ey}
    unsigned int wB[4] = {f01.y, f01.w, f23.y, f23.w};   // {ez, src'}
    unsigned int xA[4] = {xm01.x, xm01.z, xm23.x, xm23.z};
    unsigned int yA[4] = {ym01.x, ym01.z, ym23.x, ym23.z};
    float ezmf[4] = { h_lo(zmF.y), h_lo(wB[0]), h_lo(wB[1]), h_lo(wB[2]) };
    float rr[4] = {rv.x, rv.y, rv.z, rv.w};

    float out[4];
#pragma unroll
    for (int j = 0; j < 4; ++j) {
        float ex = h_lo(wA[j]), ey = h_hi(wA[j]);
        float ez = h_lo(wB[j]), sc = h_hi(wB[j]);
        float exm = h_lo(xA[j]);
        float eym = h_hi(yA[j]);
        float s = ex * pxp[j] + exm * pxm[j]
                + ey * pyp[j] + eym * pym[j]
                + ez * pzp[j] + ezmf[j] * pzm[j];
        out[j] = rr[j] * s + sc;
    }
    *reinterpret_cast<float4*>(pout + g4) = make_float4(out[0], out[1], out[2], out[3]);
}

// ---------------- Jacobi sweep v2 (fallback path, verified) ----------------
__global__ void jacobi_v2(const float* __restrict__ eps,
                          const float* __restrict__ q,
                          const float* __restrict__ pin,
                          float* __restrict__ pout)
{
    int bxy = blockIdx.x;
    int b = bxy >> 14;
    int x = (bxy >> 7) & 127;
    int y = bxy & 127;
    int z = threadIdx.x;

    size_t sp = ((size_t)x * 128 + y) * 128 + z;
    size_t g  = (size_t)b * (size_t)VOX_ + sp;
    const float* E = eps + (size_t)b * 4 * (size_t)VOX_;

    float ex = E[sp];
    float ey = E[sp + (size_t)VOX_];
    float ez = E[sp + (size_t)VOX_ * 2];
    float ek = E[sp + (size_t)VOX_ * 3];
    float exm = (x > 0) ? E[sp - 16384]                 : EPS_OUT_C;
    float eym = (y > 0) ? E[sp + (size_t)VOX_ - 128]    : EPS_OUT_C;
    float ezm = (z > 0) ? E[sp + (size_t)VOX_ * 2 - 1]  : EPS_OUT_C;

    float lam = (ek - EPS_IN_C) / (EPS_OUT_C - EPS_IN_C);
    lam = fminf(fmaxf(lam, 0.0f), 1.0f);
    float denom = ex + exm + ey + eym + ez + ezm + KAPPA02_C * lam;

    float pxp = (x < 127) ? pin[g + 16384] : 0.0f;
    float pxm = (x > 0)   ? pin[g - 16384] : 0.0f;
    float pyp = (y < 127) ? pin[g + 128]   : 0.0f;
    float pym = (y > 0)   ? pin[g - 128]   : 0.0f;
    float pzp = (z < 127) ? pin[g + 1]     : 0.0f;
    float pzm = (z > 0)   ? pin[g - 1]     : 0.0f;

    float num = ex * pxp + exm * pxm + ey * pyp + eym * pym
              + ez * pzp + ezm * pzm + FOURPI_C * q[g];
    pout[g] = num / denom;
}

// ---------------- launch ----------------
extern "C" void kernel_launch(void* const* d_in, const int* in_sizes, int n_in,
                              void* d_out, int out_size, void* d_ws, size_t ws_size,
                              hipStream_t stream)
{
    const float* coords    = (const float*)d_in[0];
    const float* params    = (const float*)d_in[1];
    const int*   num_atoms = (const int*)d_in[2];

    float* q   = (float*)d_out;                       // [B][128^3]
    float* eps = q + (size_t)B_ * VOX_;               // [B][4][128^3]
    float* phi = eps + (size_t)B_ * 4 * VOX_;         // [B][128^3]

    hipMemsetAsync(q, 0, (size_t)B_ * VOX_ * sizeof(float), stream);
    hipMemsetAsync(phi, 0, (size_t)B_ * VOX_ * sizeof(float), stream);

    scatter_q_kernel<<<(B_ * N_ + 255) / 256, 256, 0, stream>>>(coords, params, num_atoms, q);
    eps_gather_v2<<<B_ * 4096, 512, 0, stream>>>(coords, params, num_atoms, eps);

    size_t faceBytes = (size_t)B_ * VOX_ * sizeof(uint2);    // 67.1 MB
    size_t rcpBytes  = (size_t)B_ * VOX_ * sizeof(float);    // 33.5 MB
    size_t phiBytes  = (size_t)B_ * VOX_ * sizeof(float);    // 33.5 MB
    size_t need = faceBytes + rcpBytes + phiBytes;           // 134.2 MB

    if (ws_size >= need) {
        uint2* Fa  = (uint2*)d_ws;
        float* Ra  = (float*)((char*)d_ws + faceBytes);
        float* tmp = (float*)((char*)d_ws + faceBytes + rcpBytes);
        coef_pack2<<<B_ * 128 * 128, 128, 0, stream>>>(eps, q, Fa, Ra);
        int jb = (int)(B_ * VOX_ / 4 / 256);
        const float* cur = phi;     // zeroed phi_0
        for (int it = 1; it <= 20; ++it) {
            float* dst = (it & 1) ? tmp : phi;   // iter 20 (even) -> phi (d_out)
            jacobi_v4<<<jb, 256, 0, stream>>>(Fa, Ra, cur, dst);
            cur = dst;
        }
    } else {
        float* tmp = (float*)d_ws;
        int jb = B_ * 128 * 128;
        const float* cur = phi;
        for (int it = 1; it <= 20; ++it) {
            float* dst = (it & 1) ? tmp : phi;
            jacobi_v2<<<jb, 128, 0, stream>>>(eps, q, cur, dst);
            cur = dst;
        }
    }
}

// Round 3
// 1234.258 us; speedup vs baseline: 1.4180x; 1.4180x over previous
//
#include <hip/hip_runtime.h>
#include <hip/hip_fp16.h>
#include <math.h>

// ---------------- problem constants ----------------
static constexpr int   B_    = 4;
static constexpr int   N_    = 4096;
static constexpr int   BOX_  = 128;
static constexpr long long VOX_ = 1LL * BOX_ * BOX_ * BOX_;   // 2097152
static constexpr float EPS_IN_C  = 6.5f;
static constexpr float EPS_OUT_C = 79.0f;
static constexpr float QCONV_C   = 7046.52f;
static constexpr float KAPPA02_C = 0.8486f;
static constexpr float FOURPI_C  = 12.566370614359172f;

// ---------------- trilinear charge scatter (verified) ----------
__global__ void scatter_q_kernel(const float* __restrict__ coords,
                                 const float* __restrict__ params,
                                 const int*   __restrict__ num_atoms,
                                 float* __restrict__ q)
{
    int a = blockIdx.x * blockDim.x + threadIdx.x;
    if (a >= B_ * N_) return;
    int b = a >> 12;
    int n = a & (N_ - 1);
    if (n >= num_atoms[b]) return;

    float cx = coords[3 * a + 0];
    float cy = coords[3 * a + 1];
    float cz = coords[3 * a + 2];
    float chg = params[2 * a + 0] * QCONV_C;

    int ix0 = (int)floorf(cx), iy0 = (int)floorf(cy), iz0 = (int)floorf(cz);
    float fx = cx - (float)ix0, fy = cy - (float)iy0, fz = cz - (float)iz0;
    float wx[2] = {1.0f - fx, fx};
    float wy[2] = {1.0f - fy, fy};
    float wz[2] = {1.0f - fz, fz};

    float* qb = q + (long long)b * VOX_;
#pragma unroll
    for (int dx = 0; dx < 2; ++dx) {
        int ix = ix0 + dx;
        if ((unsigned)ix >= 128u) continue;
#pragma unroll
        for (int dy = 0; dy < 2; ++dy) {
            int iy = iy0 + dy;
            if ((unsigned)iy >= 128u) continue;
#pragma unroll
            for (int dz = 0; dz < 2; ++dz) {
                int iz = iz0 + dz;
                if ((unsigned)iz >= 128u) continue;
                atomicAdd(&qb[((long long)ix * 128 + iy) * 128 + iz],
                          chg * wx[dx] * wy[dy] * wz[dz]);
            }
        }
    }
}

// ---------------- eps gather v2: separable per-axis weights in LDS ----------
// Weight semantics identical to verified round-5 axis_d2 (JAX wrap on negatives).
#define CAND_CAP 512
#define CHUNK 32

__global__ void eps_gather_v2(const float* __restrict__ coords,
                              const float* __restrict__ params,
                              const int*   __restrict__ num_atoms,
                              float* __restrict__ eps)   // [B][4][128^3]
{
    int tileId = blockIdx.x;            // B * 4096 tiles
    int b  = tileId >> 12;
    int t  = tileId & 4095;
    int tx = ((t >> 8) & 15) << 3;
    int ty = ((t >> 4) & 15) << 3;
    int tz = (t & 15) << 3;

    __shared__ float sx[CAND_CAP], sy[CAND_CAP], sz[CAND_CAP], sr[CAND_CAP];
    __shared__ float wts[CHUNK][9][8];   // [atom][axis*3+variant][tile pos]
    __shared__ int s_cnt;
    if (threadIdx.x == 0) s_cnt = 0;
    __syncthreads();

    int na = num_atoms[b];
    const float* cb = coords + (size_t)b * N_ * 3;
    const float* pb = params + (size_t)b * N_ * 2;

    float lox = (float)tx - 6.0f, hix = (float)tx + 14.0f;
    float loy = (float)ty - 6.0f, hiy = (float)ty + 14.0f;
    float loz = (float)tz - 6.0f, hiz = (float)tz + 14.0f;
    bool wx_ = (tx == 120), wy_ = (ty == 120), wz_ = (tz == 120);
    for (int n = threadIdx.x; n < na; n += blockDim.x) {
        float cx = cb[3 * n], cy = cb[3 * n + 1], cz = cb[3 * n + 2];
        bool okx = (cx >= lox && cx < hix) || (wx_ && cx < 6.0f);
        bool oky = (cy >= loy && cy < hiy) || (wy_ && cy < 6.0f);
        bool okz = (cz >= loz && cz < hiz) || (wz_ && cz < 6.0f);
        if (okx && oky && okz) {
            int slot = atomicAdd(&s_cnt, 1);
            if (slot < CAND_CAP) {
                sx[slot] = cx; sy[slot] = cy; sz[slot] = cz;
                sr[slot] = pb[2 * n + 1];
            }
        }
    }
    __syncthreads();
    int cnt = min(s_cnt, CAND_CAP);

    int lz = threadIdx.x & 7;
    int ly = (threadIdx.x >> 3) & 7;
    int lx = threadIdx.x >> 6;

    float r0 = 0.0f, r1 = 0.0f, r2 = 0.0f, r3 = 0.0f;

    for (int k0 = 0; k0 < cnt; k0 += CHUNK) {
        int nC = min(CHUNK, cnt - k0);
        __syncthreads();   // protect wts reuse across chunk iterations
        // Phase A: fill per-atom separable axis weights (72 expf per atom)
        for (int w = threadIdx.x; w < nC * 72; w += 512) {
            int ka  = w / 72;
            int rem = w - ka * 72;
            int vi  = rem >> 3;        // 0..8 = axis*3 + variant
            int pos = rem & 7;
            int axis = vi / 3, var = vi - axis * 3;
            int k = k0 + ka;
            float c     = (axis == 0) ? sx[k] : (axis == 1) ? sy[k] : sz[k];
            int   torig = (axis == 0) ? tx    : (axis == 1) ? ty    : tz;
            float r = sr[k];
            float sig = (var == 2) ? (r + 1.0f) * 0.5f : (r + 1.4f) * 0.5f;
            float off = (var == 0) ? 0.0f : 0.5f;
            float inv2s2 = 1.0f / (2.0f * sig * sig);
            int i = torig + pos;
            int base = (int)floorf(c - off) - 4;    // window [base, base+8]
            float wv = 0.0f;
            if ((unsigned)(i - base) <= 8u) {
                float d = (float)i + off - c;
                wv = expf(-d * d * inv2s2);
            } else if ((unsigned)(i - 128 - base) <= 8u) {   // JAX negative wrap
                float d = (float)(i - 128) + off - c;
                wv = expf(-d * d * inv2s2);
            }
            wts[ka][vi][pos] = wv;
        }
        __syncthreads();
        // Phase B: accumulate channels from separable products
        for (int ka = 0; ka < nC; ++ka) {
            float xE0 = wts[ka][0][lx], xE5 = wts[ka][1][lx], xI5 = wts[ka][2][lx];
            float yE0 = wts[ka][3][ly], yE5 = wts[ka][4][ly], yI5 = wts[ka][5][ly];
            float zE0 = wts[ka][6][lz], zE5 = wts[ka][7][lz], zI5 = wts[ka][8][lz];
            r0 += xE5 * yE0 * zE0;     // c0: off (.5,0,0)  sigE
            r1 += xE0 * yE5 * zE0;     // c1: off (0,.5,0)  sigE
            r2 += xE0 * yE0 * zE5;     // c2: off (0,0,.5)  sigE
            r3 += xI5 * yI5 * zI5;     // c3: off (.5,.5,.5) sigI
        }
    }

    int ix = tx + lx, iy = ty + ly, iz = tz + lz;
    size_t sp = ((size_t)ix * 128 + iy) * 128 + iz;
    float* eb = eps + (size_t)b * 4 * VOX_;
    eb[sp]                    = EPS_OUT_C + (EPS_IN_C - EPS_OUT_C) * fminf(fmaxf(r0, 0.0f), 1.0f);
    eb[sp + (size_t)VOX_]     = EPS_OUT_C + (EPS_IN_C - EPS_OUT_C) * fminf(fmaxf(r1, 0.0f), 1.0f);
    eb[sp + (size_t)VOX_ * 2] = EPS_OUT_C + (EPS_IN_C - EPS_OUT_C) * fminf(fmaxf(r2, 0.0f), 1.0f);
    eb[sp + (size_t)VOX_ * 3] = EPS_OUT_C + (EPS_IN_C - EPS_OUT_C) * fminf(fmaxf(r3, 0.0f), 1.0f);
}

// ---------------- coefficient pack: 8 fp16 per voxel (verified round-0) -----
// {ex,exm,ey,eym,ez,ezm}/denom and 4*pi*q/denom
__global__ void coef_pack(const float* __restrict__ eps,
                          const float* __restrict__ q,
                          uint4* __restrict__ coef)
{
    int bxy = blockIdx.x;
    int b = bxy >> 14;
    int x = (bxy >> 7) & 127;
    int y = bxy & 127;
    int z = threadIdx.x;

    size_t sp = ((size_t)x * 128 + y) * 128 + z;
    size_t g  = (size_t)b * (size_t)VOX_ + sp;
    const float* E = eps + (size_t)b * 4 * (size_t)VOX_;

    float ex = E[sp];
    float ey = E[sp + (size_t)VOX_];
    float ez = E[sp + (size_t)VOX_ * 2];
    float ek = E[sp + (size_t)VOX_ * 3];
    float exm = (x > 0) ? E[sp - 16384]                 : EPS_OUT_C;
    float eym = (y > 0) ? E[sp + (size_t)VOX_ - 128]    : EPS_OUT_C;
    float ezm = (z > 0) ? E[sp + (size_t)VOX_ * 2 - 1]  : EPS_OUT_C;

    float lam = (ek - EPS_IN_C) / (EPS_OUT_C - EPS_IN_C);
    lam = fminf(fmaxf(lam, 0.0f), 1.0f);
    float denom = ex + exm + ey + eym + ez + ezm + KAPPA02_C * lam;
    float rcp = 1.0f / denom;

    __half2 h01 = __floats2half2_rn(ex  * rcp, exm * rcp);
    __half2 h23 = __floats2half2_rn(ey  * rcp, eym * rcp);
    __half2 h45 = __floats2half2_rn(ez  * rcp, ezm * rcp);
    __half2 h67 = __floats2half2_rn(FOURPI_C * q[g] * rcp, 0.0f);
    uint4 u;
    u.x = *(unsigned int*)&h01;
    u.y = *(unsigned int*)&h23;
    u.z = *(unsigned int*)&h45;
    u.w = *(unsigned int*)&h67;
    coef[g] = u;
}

// ---------------- fused 2-step Jacobi: 3.5D x-march with LDS pipeline -------
// Each launch performs TWO Jacobi sweeps. Coef (134 MB) is read once per 2
// iterations instead of once per iteration. FP op order matches jacobi_v3
// exactly -> bitwise identical to two v3 sweeps.
#define TY 8
#define TZ 32
#define RY (TY + 2)    // 10  (step-1 ring, halo 1)
#define RZ (TZ + 2)    // 34
#define PYD (TY + 4)   // 12  (phi tile, halo 2)
#define PZD (TZ + 4)   // 36
#define SEG 32         // x-segment per block

__global__ __launch_bounds__(256)
void jacobi_f2(const uint4* __restrict__ coef,
               const float* __restrict__ pin,
               float* __restrict__ pout)
{
    int bid = blockIdx.x;                 // 1024 blocks
    int xs = bid & 3;
    int zt = (bid >> 2) & 3;
    int yt = (bid >> 4) & 15;
    int b  = bid >> 8;
    int x_lo = xs * SEG, x_hi = x_lo + SEG - 1;
    int y0 = yt * TY, z0 = zt * TZ;

    __shared__ float P[3][PYD * PZD];     // phi_in slices x-2,x-1,x
    __shared__ float S[3][RY * RZ];       // step-1 phi slices

    int tid = threadIdx.x;
    for (int i = tid; i < 3 * RY * RZ; i += 256) ((float*)S)[i] = 0.0f;
    for (int i = tid; i < 3 * PYD * PZD; i += 256) ((float*)P)[i] = 0.0f;
    __syncthreads();

    const uint4* cb = coef + (size_t)b * VOX_;
    const float* pb = pin  + (size_t)b * VOX_;
    float*       ob = pout + (size_t)b * VOX_;

    int oy = tid >> 5;                    // output column of this thread
    int oz = tid & 31;

    for (int x = x_lo - 2; x <= x_hi + 2; ++x) {
        int s0 = (x + 3) % 3;             // slot(x)     (x >= -2)
        int s1 = (x + 2) % 3;             // slot(x-1)
        int s2 = (x + 1) % 3;             // slot(x-2)

        // ---- A: load phi slice x (zero outside box: Dirichlet) ----
        {
            bool xin = (x >= 0 && x < 128);
            const float* ps = pb + (size_t)(xin ? x : 0) * 16384;
            for (int i = tid; i < PYD * PZD; i += 256) {
                int py = i / PZD, pz = i - py * PZD;
                int y = y0 - 2 + py, z = z0 - 2 + pz;
                float v = 0.0f;
                if (xin && (unsigned)y < 128u && (unsigned)z < 128u)
                    v = ps[y * 128 + z];
                P[s0][i] = v;
            }
        }
        __syncthreads();

        // ---- B: compute step-1 slice k = x-1 on the ring ----
        int k = x - 1;
        if (k >= x_lo - 1 && k <= x_hi + 1) {
            const uint4* cs = cb + (size_t)((unsigned)k < 128u ? k : 0) * 16384;
            for (int i = tid; i < RY * RZ; i += 256) {
                int ry = i / RZ, rz = i - ry * RZ;
                int y = y0 - 1 + ry, rz2 = rz, z = z0 - 1 + rz2;
                float v = 0.0f;
                if ((unsigned)k < 128u && (unsigned)y < 128u && (unsigned)z < 128u) {
                    uint4 cu = cs[y * 128 + z];
                    const __half2* h = reinterpret_cast<const __half2*>(&cu);
                    float2 a01 = __half22float2(h[0]);
                    float2 a23 = __half22float2(h[1]);
                    float2 a45 = __half22float2(h[2]);
                    float2 a67 = __half22float2(h[3]);
                    int i0 = (ry + 1) * PZD + (rz + 1);
                    v = a01.x * P[s0][i0]        // x+1 neighbor = slice x
                      + a01.y * P[s2][i0]        // x-1 neighbor = slice x-2
                      + a23.x * P[s1][i0 + PZD]
                      + a23.y * P[s1][i0 - PZD]
                      + a45.x * P[s1][i0 + 1]
                      + a45.y * P[s1][i0 - 1]
                      + a67.x;
                }
                S[s1][i] = v;
            }
        }
        __syncthreads();

        // ---- C: compute step-2 output at xo = x-2, store ----
        int xo = x - 2;
        if (xo >= x_lo && xo <= x_hi) {
            int y = y0 + oy, z = z0 + oz;
            uint4 cu = cb[(size_t)xo * 16384 + y * 128 + z];
            const __half2* h = reinterpret_cast<const __half2*>(&cu);
            float2 a01 = __half22float2(h[0]);
            float2 a23 = __half22float2(h[1]);
            float2 a45 = __half22float2(h[2]);
            float2 a67 = __half22float2(h[3]);
            int j0 = (oy + 1) * RZ + (oz + 1);
            // S slots: S1[xo] = s2(center), S1[xo+1] = s1, S1[xo-1] = s0
            float out = a01.x * S[s1][j0]
                      + a01.y * S[s0][j0]
                      + a23.x * S[s2][j0 + RZ]
                      + a23.y * S[s2][j0 - RZ]
                      + a45.x * S[s2][j0 + 1]
                      + a45.y * S[s2][j0 - 1]
                      + a67.x;
            ob[(size_t)xo * 16384 + y * 128 + z] = out;
        }
        // no sync needed here: next A writes P only; C reads S only (disjoint),
        // and the sync after next A orders C(x) before B(x+1)'s S-writes.
    }
}

// ---------------- Jacobi sweep v2 (fallback path, verified) ----------------
__global__ void jacobi_v2(const float* __restrict__ eps,
                          const float* __restrict__ q,
                          const float* __restrict__ pin,
                          float* __restrict__ pout)
{
    int bxy = blockIdx.x;
    int b = bxy >> 14;
    int x = (bxy >> 7) & 127;
    int y = bxy & 127;
    int z = threadIdx.x;

    size_t sp = ((size_t)x * 128 + y) * 128 + z;
    size_t g  = (size_t)b * (size_t)VOX_ + sp;
    const float* E = eps + (size_t)b * 4 * (size_t)VOX_;

    float ex = E[sp];
    float ey = E[sp + (size_t)VOX_];
    float ez = E[sp + (size_t)VOX_ * 2];
    float ek = E[sp + (size_t)VOX_ * 3];
    float exm = (x > 0) ? E[sp - 16384]                 : EPS_OUT_C;
    float eym = (y > 0) ? E[sp + (size_t)VOX_ - 128]    : EPS_OUT_C;
    float ezm = (z > 0) ? E[sp + (size_t)VOX_ * 2 - 1]  : EPS_OUT_C;

    float lam = (ek - EPS_IN_C) / (EPS_OUT_C - EPS_IN_C);
    lam = fminf(fmaxf(lam, 0.0f), 1.0f);
    float denom = ex + exm + ey + eym + ez + ezm + KAPPA02_C * lam;

    float pxp = (x < 127) ? pin[g + 16384] : 0.0f;
    float pxm = (x > 0)   ? pin[g - 16384] : 0.0f;
    float pyp = (y < 127) ? pin[g + 128]   : 0.0f;
    float pym = (y > 0)   ? pin[g - 128]   : 0.0f;
    float pzp = (z < 127) ? pin[g + 1]     : 0.0f;
    float pzm = (z > 0)   ? pin[g - 1]     : 0.0f;

    float num = ex * pxp + exm * pxm + ey * pyp + eym * pym
              + ez * pzp + ezm * pzm + FOURPI_C * q[g];
    pout[g] = num / denom;
}

// ---------------- launch ----------------
extern "C" void kernel_launch(void* const* d_in, const int* in_sizes, int n_in,
                              void* d_out, int out_size, void* d_ws, size_t ws_size,
                              hipStream_t stream)
{
    const float* coords    = (const float*)d_in[0];
    const float* params    = (const float*)d_in[1];
    const int*   num_atoms = (const int*)d_in[2];

    float* q   = (float*)d_out;                       // [B][128^3]
    float* eps = q + (size_t)B_ * VOX_;               // [B][4][128^3]
    float* phi = eps + (size_t)B_ * 4 * VOX_;         // [B][128^3]

    hipMemsetAsync(q, 0, (size_t)B_ * VOX_ * sizeof(float), stream);
    hipMemsetAsync(phi, 0, (size_t)B_ * VOX_ * sizeof(float), stream);

    scatter_q_kernel<<<(B_ * N_ + 255) / 256, 256, 0, stream>>>(coords, params, num_atoms, q);
    eps_gather_v2<<<B_ * 4096, 512, 0, stream>>>(coords, params, num_atoms, eps);

    size_t coefBytes = (size_t)B_ * VOX_ * sizeof(uint4);              // 134 MB
    size_t need = coefBytes + (size_t)B_ * VOX_ * sizeof(float);       // +33.5 MB

    if (ws_size >= need) {
        uint4* coefA = (uint4*)d_ws;
        float* tmp   = (float*)((char*)d_ws + coefBytes);
        coef_pack<<<B_ * 128 * 128, 128, 0, stream>>>(eps, q, coefA);
        const float* cur = phi;     // zeroed phi_0
        for (int it = 1; it <= 10; ++it) {          // 10 fused launches = 20 sweeps
            float* dst = (it & 1) ? tmp : phi;      // it=10 (even) -> phi (d_out)
            jacobi_f2<<<B_ * 16 * 4 * 4, 256, 0, stream>>>(coefA, cur, dst);
            cur = dst;
        }
    } else {
        float* tmp = (float*)d_ws;
        int jb = B_ * 128 * 128;
        const float* cur = phi;
        for (int it = 1; it <= 20; ++it) {
            float* dst = (it & 1) ? tmp : phi;
            jacobi_v2<<<jb, 128, 0, stream>>>(eps, q, cur, dst);
            cur = dst;
        }
    }
}

// Round 4
// 1168.323 us; speedup vs baseline: 1.4980x; 1.0564x over previous
//
#include <hip/hip_runtime.h>
#include <hip/hip_fp16.h>
#include <math.h>

// ---------------- problem constants ----------------
static constexpr int   B_    = 4;
static constexpr int   N_    = 4096;
static constexpr int   BOX_  = 128;
static constexpr long long VOX_ = 1LL * BOX_ * BOX_ * BOX_;   // 2097152
static constexpr float EPS_IN_C  = 6.5f;
static constexpr float EPS_OUT_C = 79.0f;
static constexpr float QCONV_C   = 7046.52f;
static constexpr float KAPPA02_C = 0.8486f;
static constexpr float FOURPI_C  = 12.566370614359172f;

// ---------------- trilinear charge scatter (verified) ----------
__global__ void scatter_q_kernel(const float* __restrict__ coords,
                                 const float* __restrict__ params,
                                 const int*   __restrict__ num_atoms,
                                 float* __restrict__ q)
{
    int a = blockIdx.x * blockDim.x + threadIdx.x;
    if (a >= B_ * N_) return;
    int b = a >> 12;
    int n = a & (N_ - 1);
    if (n >= num_atoms[b]) return;

    float cx = coords[3 * a + 0];
    float cy = coords[3 * a + 1];
    float cz = coords[3 * a + 2];
    float chg = params[2 * a + 0] * QCONV_C;

    int ix0 = (int)floorf(cx), iy0 = (int)floorf(cy), iz0 = (int)floorf(cz);
    float fx = cx - (float)ix0, fy = cy - (float)iy0, fz = cz - (float)iz0;
    float wx[2] = {1.0f - fx, fx};
    float wy[2] = {1.0f - fy, fy};
    float wz[2] = {1.0f - fz, fz};

    float* qb = q + (long long)b * VOX_;
#pragma unroll
    for (int dx = 0; dx < 2; ++dx) {
        int ix = ix0 + dx;
        if ((unsigned)ix >= 128u) continue;
#pragma unroll
        for (int dy = 0; dy < 2; ++dy) {
            int iy = iy0 + dy;
            if ((unsigned)iy >= 128u) continue;
#pragma unroll
            for (int dz = 0; dz < 2; ++dz) {
                int iz = iz0 + dz;
                if ((unsigned)iz >= 128u) continue;
                atomicAdd(&qb[((long long)ix * 128 + iy) * 128 + iz],
                          chg * wx[dx] * wy[dy] * wz[dz]);
            }
        }
    }
}

// ---------------- eps gather v2: separable per-axis weights in LDS ----------
// Weight semantics identical to verified round-5 axis_d2 (JAX wrap on negatives).
#define CAND_CAP 512
#define CHUNK 32

__global__ void eps_gather_v2(const float* __restrict__ coords,
                              const float* __restrict__ params,
                              const int*   __restrict__ num_atoms,
                              float* __restrict__ eps)   // [B][4][128^3]
{
    int tileId = blockIdx.x;            // B * 4096 tiles
    int b  = tileId >> 12;
    int t  = tileId & 4095;
    int tx = ((t >> 8) & 15) << 3;
    int ty = ((t >> 4) & 15) << 3;
    int tz = (t & 15) << 3;

    __shared__ float sx[CAND_CAP], sy[CAND_CAP], sz[CAND_CAP], sr[CAND_CAP];
    __shared__ float wts[CHUNK][9][8];   // [atom][axis*3+variant][tile pos]
    __shared__ int s_cnt;
    if (threadIdx.x == 0) s_cnt = 0;
    __syncthreads();

    int na = num_atoms[b];
    const float* cb = coords + (size_t)b * N_ * 3;
    const float* pb = params + (size_t)b * N_ * 2;

    float lox = (float)tx - 6.0f, hix = (float)tx + 14.0f;
    float loy = (float)ty - 6.0f, hiy = (float)ty + 14.0f;
    float loz = (float)tz - 6.0f, hiz = (float)tz + 14.0f;
    bool wx_ = (tx == 120), wy_ = (ty == 120), wz_ = (tz == 120);
    for (int n = threadIdx.x; n < na; n += blockDim.x) {
        float cx = cb[3 * n], cy = cb[3 * n + 1], cz = cb[3 * n + 2];
        bool okx = (cx >= lox && cx < hix) || (wx_ && cx < 6.0f);
        bool oky = (cy >= loy && cy < hiy) || (wy_ && cy < 6.0f);
        bool okz = (cz >= loz && cz < hiz) || (wz_ && cz < 6.0f);
        if (okx && oky && okz) {
            int slot = atomicAdd(&s_cnt, 1);
            if (slot < CAND_CAP) {
                sx[slot] = cx; sy[slot] = cy; sz[slot] = cz;
                sr[slot] = pb[2 * n + 1];
            }
        }
    }
    __syncthreads();
    int cnt = min(s_cnt, CAND_CAP);

    int lz = threadIdx.x & 7;
    int ly = (threadIdx.x >> 3) & 7;
    int lx = threadIdx.x >> 6;

    float r0 = 0.0f, r1 = 0.0f, r2 = 0.0f, r3 = 0.0f;

    for (int k0 = 0; k0 < cnt; k0 += CHUNK) {
        int nC = min(CHUNK, cnt - k0);
        __syncthreads();   // protect wts reuse across chunk iterations
        // Phase A: fill per-atom separable axis weights (72 expf per atom)
        for (int w = threadIdx.x; w < nC * 72; w += 512) {
            int ka  = w / 72;
            int rem = w - ka * 72;
            int vi  = rem >> 3;        // 0..8 = axis*3 + variant
            int pos = rem & 7;
            int axis = vi / 3, var = vi - axis * 3;
            int k = k0 + ka;
            float c     = (axis == 0) ? sx[k] : (axis == 1) ? sy[k] : sz[k];
            int   torig = (axis == 0) ? tx    : (axis == 1) ? ty    : tz;
            float r = sr[k];
            float sig = (var == 2) ? (r + 1.0f) * 0.5f : (r + 1.4f) * 0.5f;
            float off = (var == 0) ? 0.0f : 0.5f;
            float inv2s2 = 1.0f / (2.0f * sig * sig);
            int i = torig + pos;
            int base = (int)floorf(c - off) - 4;    // window [base, base+8]
            float wv = 0.0f;
            if ((unsigned)(i - base) <= 8u) {
                float d = (float)i + off - c;
                wv = expf(-d * d * inv2s2);
            } else if ((unsigned)(i - 128 - base) <= 8u) {   // JAX negative wrap
                float d = (float)(i - 128) + off - c;
                wv = expf(-d * d * inv2s2);
            }
            wts[ka][vi][pos] = wv;
        }
        __syncthreads();
        // Phase B: accumulate channels from separable products
        for (int ka = 0; ka < nC; ++ka) {
            float xE0 = wts[ka][0][lx], xE5 = wts[ka][1][lx], xI5 = wts[ka][2][lx];
            float yE0 = wts[ka][3][ly], yE5 = wts[ka][4][ly], yI5 = wts[ka][5][ly];
            float zE0 = wts[ka][6][lz], zE5 = wts[ka][7][lz], zI5 = wts[ka][8][lz];
            r0 += xE5 * yE0 * zE0;     // c0: off (.5,0,0)  sigE
            r1 += xE0 * yE5 * zE0;     // c1: off (0,.5,0)  sigE
            r2 += xE0 * yE0 * zE5;     // c2: off (0,0,.5)  sigE
            r3 += xI5 * yI5 * zI5;     // c3: off (.5,.5,.5) sigI
        }
    }

    int ix = tx + lx, iy = ty + ly, iz = tz + lz;
    size_t sp = ((size_t)ix * 128 + iy) * 128 + iz;
    float* eb = eps + (size_t)b * 4 * VOX_;
    eb[sp]                    = EPS_OUT_C + (EPS_IN_C - EPS_OUT_C) * fminf(fmaxf(r0, 0.0f), 1.0f);
    eb[sp + (size_t)VOX_]     = EPS_OUT_C + (EPS_IN_C - EPS_OUT_C) * fminf(fmaxf(r1, 0.0f), 1.0f);
    eb[sp + (size_t)VOX_ * 2] = EPS_OUT_C + (EPS_IN_C - EPS_OUT_C) * fminf(fmaxf(r2, 0.0f), 1.0f);
    eb[sp + (size_t)VOX_ * 3] = EPS_OUT_C + (EPS_IN_C - EPS_OUT_C) * fminf(fmaxf(r3, 0.0f), 1.0f);
}

// ---------------- coefficient pack: 8 fp16 per voxel (verified round-0) -----
// {ex,exm,ey,eym,ez,ezm}/denom and 4*pi*q/denom
__global__ void coef_pack(const float* __restrict__ eps,
                          const float* __restrict__ q,
                          uint4* __restrict__ coef)
{
    int bxy = blockIdx.x;
    int b = bxy >> 14;
    int x = (bxy >> 7) & 127;
    int y = bxy & 127;
    int z = threadIdx.x;

    size_t sp = ((size_t)x * 128 + y) * 128 + z;
    size_t g  = (size_t)b * (size_t)VOX_ + sp;
    const float* E = eps + (size_t)b * 4 * (size_t)VOX_;

    float ex = E[sp];
    float ey = E[sp + (size_t)VOX_];
    float ez = E[sp + (size_t)VOX_ * 2];
    float ek = E[sp + (size_t)VOX_ * 3];
    float exm = (x > 0) ? E[sp - 16384]                 : EPS_OUT_C;
    float eym = (y > 0) ? E[sp + (size_t)VOX_ - 128]    : EPS_OUT_C;
    float ezm = (z > 0) ? E[sp + (size_t)VOX_ * 2 - 1]  : EPS_OUT_C;

    float lam = (ek - EPS_IN_C) / (EPS_OUT_C - EPS_IN_C);
    lam = fminf(fmaxf(lam, 0.0f), 1.0f);
    float denom = ex + exm + ey + eym + ez + ezm + KAPPA02_C * lam;
    float rcp = 1.0f / denom;

    __half2 h01 = __floats2half2_rn(ex  * rcp, exm * rcp);
    __half2 h23 = __floats2half2_rn(ey  * rcp, eym * rcp);
    __half2 h45 = __floats2half2_rn(ez  * rcp, ezm * rcp);
    __half2 h67 = __floats2half2_rn(FOURPI_C * q[g] * rcp, 0.0f);
    uint4 u;
    u.x = *(unsigned int*)&h01;
    u.y = *(unsigned int*)&h23;
    u.z = *(unsigned int*)&h45;
    u.w = *(unsigned int*)&h67;
    coef[g] = u;
}

// ---------------- fused 2-step Jacobi with LDS coef cache -------------------
// Each launch performs TWO Jacobi sweeps. Coef slice j is loaded from global
// ONCE (phase B, iter x=j+1), staged in LDS, and reused by phase C (iter j+2).
// FP op order matches jacobi_v3 exactly -> bitwise identical to two v3 sweeps.
#define TY 8
#define TZ 32
#define RY (TY + 2)    // 10  (step-1 ring, halo 1)
#define RZ (TZ + 2)    // 34
#define PYD (TY + 4)   // 12  (phi tile, halo 2)
#define PZD (TZ + 4)   // 36
#define SEG 32         // x-segment per block

__global__ __launch_bounds__(256)
void jacobi_f2(const uint4* __restrict__ coef,
               const float* __restrict__ pin,
               float* __restrict__ pout)
{
    int bid = blockIdx.x;                 // 1024 blocks
    int xs = bid & 3;
    int zt = (bid >> 2) & 3;
    int yt = (bid >> 4) & 15;
    int b  = bid >> 8;
    int x_lo = xs * SEG, x_hi = x_lo + SEG - 1;
    int y0 = yt * TY, z0 = zt * TZ;

    __shared__ float P[3][PYD * PZD];     // phi_in slices x-2,x-1,x
    __shared__ float S[3][RY * RZ];       // step-1 phi slices
    __shared__ uint4 CF[2][RY * RZ];      // coef ring slices (x parity slots)

    int tid = threadIdx.x;
    for (int i = tid; i < 3 * RY * RZ; i += 256) ((float*)S)[i] = 0.0f;
    for (int i = tid; i < 3 * PYD * PZD; i += 256) ((float*)P)[i] = 0.0f;
    __syncthreads();

    const uint4* cb = coef + (size_t)b * VOX_;
    const float* pb = pin  + (size_t)b * VOX_;
    float*       ob = pout + (size_t)b * VOX_;

    int oy = tid >> 5;                    // output column of this thread
    int oz = tid & 31;

    for (int x = x_lo - 2; x <= x_hi + 2; ++x) {
        int s0 = (x + 3) % 3;             // slot(x)     (x >= -2)
        int s1 = (x + 2) % 3;             // slot(x-1)
        int s2 = (x + 1) % 3;             // slot(x-2)

        // ---- A: load phi slice x (zero outside box: Dirichlet) ----
        {
            bool xin = (x >= 0 && x < 128);
            const float* ps = pb + (size_t)(xin ? x : 0) * 16384;
            for (int i = tid; i < PYD * PZD; i += 256) {
                int py = i / PZD, pz = i - py * PZD;
                int y = y0 - 2 + py, z = z0 - 2 + pz;
                float v = 0.0f;
                if (xin && (unsigned)y < 128u && (unsigned)z < 128u)
                    v = ps[y * 128 + z];
                P[s0][i] = v;
            }
        }
        __syncthreads();

        // ---- B: load coef ring for slice k = x-1 into CF, compute step-1 ----
        int k = x - 1;
        if (k >= x_lo - 1 && k <= x_hi + 1) {
            const uint4* cs = cb + (size_t)((unsigned)k < 128u ? k : 0) * 16384;
            uint4* cf = CF[k & 1];
            for (int i = tid; i < RY * RZ; i += 256) {
                int ry = i / RZ, rz = i - ry * RZ;
                int y = y0 - 1 + ry, z = z0 - 1 + rz;
                float v = 0.0f;
                bool inb = ((unsigned)k < 128u && (unsigned)y < 128u && (unsigned)z < 128u);
                uint4 cu = make_uint4(0u, 0u, 0u, 0u);
                if (inb) {
                    cu = cs[y * 128 + z];
                    const __half2* h = reinterpret_cast<const __half2*>(&cu);
                    float2 a01 = __half22float2(h[0]);
                    float2 a23 = __half22float2(h[1]);
                    float2 a45 = __half22float2(h[2]);
                    float2 a67 = __half22float2(h[3]);
                    int i0 = (ry + 1) * PZD + (rz + 1);
                    v = a01.x * P[s0][i0]        // x+1 neighbor = slice x
                      + a01.y * P[s2][i0]        // x-1 neighbor = slice x-2
                      + a23.x * P[s1][i0 + PZD]
                      + a23.y * P[s1][i0 - PZD]
                      + a45.x * P[s1][i0 + 1]
                      + a45.y * P[s1][i0 - 1]
                      + a67.x;
                }
                cf[i] = cu;
                S[s1][i] = v;
            }
        }
        __syncthreads();

        // ---- C: compute step-2 output at xo = x-2 from LDS coef, store ----
        int xo = x - 2;
        if (xo >= x_lo && xo <= x_hi) {
            int y = y0 + oy, z = z0 + oz;
            int j0 = (oy + 1) * RZ + (oz + 1);
            // coef slice xo was staged by B at iter x-1 into slot (xo & 1)
            uint4 cu = CF[xo & 1][j0];
            const __half2* h = reinterpret_cast<const __half2*>(&cu);
            float2 a01 = __half22float2(h[0]);
            float2 a23 = __half22float2(h[1]);
            float2 a45 = __half22float2(h[2]);
            float2 a67 = __half22float2(h[3]);
            // S slots: S1[xo] = s2(center), S1[xo+1] = s1, S1[xo-1] = s0
            float out = a01.x * S[s1][j0]
                      + a01.y * S[s0][j0]
                      + a23.x * S[s2][j0 + RZ]
                      + a23.y * S[s2][j0 - RZ]
                      + a45.x * S[s2][j0 + 1]
                      + a45.y * S[s2][j0 - 1]
                      + a67.x;
            ob[(size_t)xo * 16384 + y * 128 + z] = out;
        }
        // no sync needed here: next A writes P only; C reads S/CF only, and the
        // sync after next A orders C(x) before B(x+1)'s S/CF writes.
    }
}

// ---------------- Jacobi sweep v2 (fallback path, verified) ----------------
__global__ void jacobi_v2(const float* __restrict__ eps,
                          const float* __restrict__ q,
                          const float* __restrict__ pin,
                          float* __restrict__ pout)
{
    int bxy = blockIdx.x;
    int b = bxy >> 14;
    int x = (bxy >> 7) & 127;
    int y = bxy & 127;
    int z = threadIdx.x;

    size_t sp = ((size_t)x * 128 + y) * 128 + z;
    size_t g  = (size_t)b * (size_t)VOX_ + sp;
    const float* E = eps + (size_t)b * 4 * (size_t)VOX_;

    float ex = E[sp];
    float ey = E[sp + (size_t)VOX_];
    float ez = E[sp + (size_t)VOX_ * 2];
    float ek = E[sp + (size_t)VOX_ * 3];
    float exm = (x > 0) ? E[sp - 16384]                 : EPS_OUT_C;
    float eym = (y > 0) ? E[sp + (size_t)VOX_ - 128]    : EPS_OUT_C;
    float ezm = (z > 0) ? E[sp + (size_t)VOX_ * 2 - 1]  : EPS_OUT_C;

    float lam = (ek - EPS_IN_C) / (EPS_OUT_C - EPS_IN_C);
    lam = fminf(fmaxf(lam, 0.0f), 1.0f);
    float denom = ex + exm + ey + eym + ez + ezm + KAPPA02_C * lam;

    float pxp = (x < 127) ? pin[g + 16384] : 0.0f;
    float pxm = (x > 0)   ? pin[g - 16384] : 0.0f;
    float pyp = (y < 127) ? pin[g + 128]   : 0.0f;
    float pym = (y > 0)   ? pin[g - 128]   : 0.0f;
    float pzp = (z < 127) ? pin[g + 1]     : 0.0f;
    float pzm = (z > 0)   ? pin[g - 1]     : 0.0f;

    float num = ex * pxp + exm * pxm + ey * pyp + eym * pym
              + ez * pzp + ezm * pzm + FOURPI_C * q[g];
    pout[g] = num / denom;
}

// ---------------- launch ----------------
extern "C" void kernel_launch(void* const* d_in, const int* in_sizes, int n_in,
                              void* d_out, int out_size, void* d_ws, size_t ws_size,
                              hipStream_t stream)
{
    const float* coords    = (const float*)d_in[0];
    const float* params    = (const float*)d_in[1];
    const int*   num_atoms = (const int*)d_in[2];

    float* q   = (float*)d_out;                       // [B][128^3]
    float* eps = q + (size_t)B_ * VOX_;               // [B][4][128^3]
    float* phi = eps + (size_t)B_ * 4 * VOX_;         // [B][128^3]

    hipMemsetAsync(q, 0, (size_t)B_ * VOX_ * sizeof(float), stream);
    hipMemsetAsync(phi, 0, (size_t)B_ * VOX_ * sizeof(float), stream);

    scatter_q_kernel<<<(B_ * N_ + 255) / 256, 256, 0, stream>>>(coords, params, num_atoms, q);
    eps_gather_v2<<<B_ * 4096, 512, 0, stream>>>(coords, params, num_atoms, eps);

    size_t coefBytes = (size_t)B_ * VOX_ * sizeof(uint4);              // 134 MB
    size_t need = coefBytes + (size_t)B_ * VOX_ * sizeof(float);       // +33.5 MB

    if (ws_size >= need) {
        uint4* coefA = (uint4*)d_ws;
        float* tmp   = (float*)((char*)d_ws + coefBytes);
        coef_pack<<<B_ * 128 * 128, 128, 0, stream>>>(eps, q, coefA);
        const float* cur = phi;     // zeroed phi_0
        for (int it = 1; it <= 10; ++it) {          // 10 fused launches = 20 sweeps
            float* dst = (it & 1) ? tmp : phi;      // it=10 (even) -> phi (d_out)
            jacobi_f2<<<B_ * 16 * 4 * 4, 256, 0, stream>>>(coefA, cur, dst);
            cur = dst;
        }
    } else {
        float* tmp = (float*)d_ws;
        int jb = B_ * 128 * 128;
        const float* cur = phi;
        for (int it = 1; it <= 20; ++it) {
            float* dst = (it & 1) ? tmp : phi;
            jacobi_v2<<<jb, 128, 0, stream>>>(eps, q, cur, dst);
            cur = dst;
        }
    }
}

// Round 5
// 924.219 us; speedup vs baseline: 1.8937x; 1.2641x over previous
//
#include <hip/hip_runtime.h>
#include <hip/hip_fp16.h>
#include <math.h>

// ---------------- problem constants ----------------
static constexpr int   B_    = 4;
static constexpr int   N_    = 4096;
static constexpr int   BOX_  = 128;
static constexpr long long VOX_ = 1LL * BOX_ * BOX_ * BOX_;   // 2097152
static constexpr float EPS_IN_C  = 6.5f;
static constexpr float EPS_OUT_C = 79.0f;
static constexpr float QCONV_C   = 7046.52f;
static constexpr float KAPPA02_C = 0.8486f;
static constexpr float FOURPI_C  = 12.566370614359172f;

// ---------------- trilinear charge scatter (verified) ----------
__global__ void scatter_q_kernel(const float* __restrict__ coords,
                                 const float* __restrict__ params,
                                 const int*   __restrict__ num_atoms,
                                 float* __restrict__ q)
{
    int a = blockIdx.x * blockDim.x + threadIdx.x;
    if (a >= B_ * N_) return;
    int b = a >> 12;
    int n = a & (N_ - 1);
    if (n >= num_atoms[b]) return;

    float cx = coords[3 * a + 0];
    float cy = coords[3 * a + 1];
    float cz = coords[3 * a + 2];
    float chg = params[2 * a + 0] * QCONV_C;

    int ix0 = (int)floorf(cx), iy0 = (int)floorf(cy), iz0 = (int)floorf(cz);
    float fx = cx - (float)ix0, fy = cy - (float)iy0, fz = cz - (float)iz0;
    float wx[2] = {1.0f - fx, fx};
    float wy[2] = {1.0f - fy, fy};
    float wz[2] = {1.0f - fz, fz};

    float* qb = q + (long long)b * VOX_;
#pragma unroll
    for (int dx = 0; dx < 2; ++dx) {
        int ix = ix0 + dx;
        if ((unsigned)ix >= 128u) continue;
#pragma unroll
        for (int dy = 0; dy < 2; ++dy) {
            int iy = iy0 + dy;
            if ((unsigned)iy >= 128u) continue;
#pragma unroll
            for (int dz = 0; dz < 2; ++dz) {
                int iz = iz0 + dz;
                if ((unsigned)iz >= 128u) continue;
                atomicAdd(&qb[((long long)ix * 128 + iy) * 128 + iz],
                          chg * wx[dx] * wy[dy] * wz[dz]);
            }
        }
    }
}

// ---------------- eps gather v2: separable per-axis weights in LDS ----------
// Weight semantics identical to verified round-5 axis_d2 (JAX wrap on negatives).
#define CAND_CAP 512
#define CHUNK 32

__global__ void eps_gather_v2(const float* __restrict__ coords,
                              const float* __restrict__ params,
                              const int*   __restrict__ num_atoms,
                              float* __restrict__ eps)   // [B][4][128^3]
{
    int tileId = blockIdx.x;            // B * 4096 tiles
    int b  = tileId >> 12;
    int t  = tileId & 4095;
    int tx = ((t >> 8) & 15) << 3;
    int ty = ((t >> 4) & 15) << 3;
    int tz = (t & 15) << 3;

    __shared__ float sx[CAND_CAP], sy[CAND_CAP], sz[CAND_CAP], sr[CAND_CAP];
    __shared__ float wts[CHUNK][9][8];   // [atom][axis*3+variant][tile pos]
    __shared__ int s_cnt;
    if (threadIdx.x == 0) s_cnt = 0;
    __syncthreads();

    int na = num_atoms[b];
    const float* cb = coords + (size_t)b * N_ * 3;
    const float* pb = params + (size_t)b * N_ * 2;

    float lox = (float)tx - 6.0f, hix = (float)tx + 14.0f;
    float loy = (float)ty - 6.0f, hiy = (float)ty + 14.0f;
    float loz = (float)tz - 6.0f, hiz = (float)tz + 14.0f;
    bool wx_ = (tx == 120), wy_ = (ty == 120), wz_ = (tz == 120);
    for (int n = threadIdx.x; n < na; n += blockDim.x) {
        float cx = cb[3 * n], cy = cb[3 * n + 1], cz = cb[3 * n + 2];
        bool okx = (cx >= lox && cx < hix) || (wx_ && cx < 6.0f);
        bool oky = (cy >= loy && cy < hiy) || (wy_ && cy < 6.0f);
        bool okz = (cz >= loz && cz < hiz) || (wz_ && cz < 6.0f);
        if (okx && oky && okz) {
            int slot = atomicAdd(&s_cnt, 1);
            if (slot < CAND_CAP) {
                sx[slot] = cx; sy[slot] = cy; sz[slot] = cz;
                sr[slot] = pb[2 * n + 1];
            }
        }
    }
    __syncthreads();
    int cnt = min(s_cnt, CAND_CAP);

    int lz = threadIdx.x & 7;
    int ly = (threadIdx.x >> 3) & 7;
    int lx = threadIdx.x >> 6;

    float r0 = 0.0f, r1 = 0.0f, r2 = 0.0f, r3 = 0.0f;

    for (int k0 = 0; k0 < cnt; k0 += CHUNK) {
        int nC = min(CHUNK, cnt - k0);
        __syncthreads();   // protect wts reuse across chunk iterations
        // Phase A: fill per-atom separable axis weights (72 expf per atom)
        for (int w = threadIdx.x; w < nC * 72; w += 512) {
            int ka  = w / 72;
            int rem = w - ka * 72;
            int vi  = rem >> 3;        // 0..8 = axis*3 + variant
            int pos = rem & 7;
            int axis = vi / 3, var = vi - axis * 3;
            int k = k0 + ka;
            float c     = (axis == 0) ? sx[k] : (axis == 1) ? sy[k] : sz[k];
            int   torig = (axis == 0) ? tx    : (axis == 1) ? ty    : tz;
            float r = sr[k];
            float sig = (var == 2) ? (r + 1.0f) * 0.5f : (r + 1.4f) * 0.5f;
            float off = (var == 0) ? 0.0f : 0.5f;
            float inv2s2 = 1.0f / (2.0f * sig * sig);
            int i = torig + pos;
            int base = (int)floorf(c - off) - 4;    // window [base, base+8]
            float wv = 0.0f;
            if ((unsigned)(i - base) <= 8u) {
                float d = (float)i + off - c;
                wv = expf(-d * d * inv2s2);
            } else if ((unsigned)(i - 128 - base) <= 8u) {   // JAX negative wrap
                float d = (float)(i - 128) + off - c;
                wv = expf(-d * d * inv2s2);
            }
            wts[ka][vi][pos] = wv;
        }
        __syncthreads();
        // Phase B: accumulate channels from separable products
        for (int ka = 0; ka < nC; ++ka) {
            float xE0 = wts[ka][0][lx], xE5 = wts[ka][1][lx], xI5 = wts[ka][2][lx];
            float yE0 = wts[ka][3][ly], yE5 = wts[ka][4][ly], yI5 = wts[ka][5][ly];
            float zE0 = wts[ka][6][lz], zE5 = wts[ka][7][lz], zI5 = wts[ka][8][lz];
            r0 += xE5 * yE0 * zE0;     // c0: off (.5,0,0)  sigE
            r1 += xE0 * yE5 * zE0;     // c1: off (0,.5,0)  sigE
            r2 += xE0 * yE0 * zE5;     // c2: off (0,0,.5)  sigE
            r3 += xI5 * yI5 * zI5;     // c3: off (.5,.5,.5) sigI
        }
    }

    int ix = tx + lx, iy = ty + ly, iz = tz + lz;
    size_t sp = ((size_t)ix * 128 + iy) * 128 + iz;
    float* eb = eps + (size_t)b * 4 * VOX_;
    eb[sp]                    = EPS_OUT_C + (EPS_IN_C - EPS_OUT_C) * fminf(fmaxf(r0, 0.0f), 1.0f);
    eb[sp + (size_t)VOX_]     = EPS_OUT_C + (EPS_IN_C - EPS_OUT_C) * fminf(fmaxf(r1, 0.0f), 1.0f);
    eb[sp + (size_t)VOX_ * 2] = EPS_OUT_C + (EPS_IN_C - EPS_OUT_C) * fminf(fmaxf(r2, 0.0f), 1.0f);
    eb[sp + (size_t)VOX_ * 3] = EPS_OUT_C + (EPS_IN_C - EPS_OUT_C) * fminf(fmaxf(r3, 0.0f), 1.0f);
}

// ---------------- coefficient pack + fold of Jacobi sweep 1 -----------------
// {ex,exm,ey,eym,ez,ezm}/denom and 4*pi*q/denom packed as 8 fp16.
// Since phi_0 == 0, sweep-1 output is exactly float(half(4*pi*q*rcp)) ->
// written directly to phi1 (bitwise identical to jacobi_v3 on zero input).
__global__ void coef_pack(const float* __restrict__ eps,
                          const float* __restrict__ q,
                          uint4* __restrict__ coef,
                          float* __restrict__ phi1)
{
    int bxy = blockIdx.x;
    int b = bxy >> 14;
    int x = (bxy >> 7) & 127;
    int y = bxy & 127;
    int z = threadIdx.x;

    size_t sp = ((size_t)x * 128 + y) * 128 + z;
    size_t g  = (size_t)b * (size_t)VOX_ + sp;
    const float* E = eps + (size_t)b * 4 * (size_t)VOX_;

    float ex = E[sp];
    float ey = E[sp + (size_t)VOX_];
    float ez = E[sp + (size_t)VOX_ * 2];
    float ek = E[sp + (size_t)VOX_ * 3];
    float exm = (x > 0) ? E[sp - 16384]                 : EPS_OUT_C;
    float eym = (y > 0) ? E[sp + (size_t)VOX_ - 128]    : EPS_OUT_C;
    float ezm = (z > 0) ? E[sp + (size_t)VOX_ * 2 - 1]  : EPS_OUT_C;

    float lam = (ek - EPS_IN_C) / (EPS_OUT_C - EPS_IN_C);
    lam = fminf(fmaxf(lam, 0.0f), 1.0f);
    float denom = ex + exm + ey + eym + ez + ezm + KAPPA02_C * lam;
    float rcp = 1.0f / denom;

    __half2 h01 = __floats2half2_rn(ex  * rcp, exm * rcp);
    __half2 h23 = __floats2half2_rn(ey  * rcp, eym * rcp);
    __half2 h45 = __floats2half2_rn(ez  * rcp, ezm * rcp);
    __half2 h67 = __floats2half2_rn(FOURPI_C * q[g] * rcp, 0.0f);
    uint4 u;
    u.x = *(unsigned int*)&h01;
    u.y = *(unsigned int*)&h23;
    u.z = *(unsigned int*)&h45;
    u.w = *(unsigned int*)&h67;
    coef[g] = u;
    phi1[g] = __half22float2(h67).x;   // sweep-1 result (phi_0 == 0)
}

// ---------------- fused 2-step Jacobi with LDS coef cache -------------------
// Each launch performs TWO Jacobi sweeps. Coef slice j is loaded from global
// ONCE (phase B, iter x=j+1), its 8x32 center staged in LDS, reused by C.
// FP op order matches jacobi_v3 exactly -> bitwise identical to two v3 sweeps.
#define TY 8
#define TZ 32
#define RY (TY + 2)    // 10  (step-1 ring, halo 1)
#define RZ (TZ + 2)    // 34
#define PYD (TY + 4)   // 12  (phi tile, halo 2)
#define PZD (TZ + 4)   // 36
#define SEG 16         // x-segment per block (16 -> 2048 blocks = 8/CU)

__global__ __launch_bounds__(256)
void jacobi_f2(const uint4* __restrict__ coef,
               const float* __restrict__ pin,
               float* __restrict__ pout)
{
    int bid = blockIdx.x;                 // 2048 blocks
    int xs = bid & 7;
    int zt = (bid >> 3) & 3;
    int yt = (bid >> 5) & 15;
    int b  = bid >> 9;
    int x_lo = xs * SEG, x_hi = x_lo + SEG - 1;
    int y0 = yt * TY, z0 = zt * TZ;

    __shared__ float P[3][PYD * PZD];     // phi_in slices x-2,x-1,x
    __shared__ float S[3][RY * RZ];       // step-1 phi slices
    __shared__ uint4 CF[2][TY * TZ];      // coef CENTER slices (x parity slots)

    int tid = threadIdx.x;
    for (int i = tid; i < 3 * RY * RZ; i += 256) ((float*)S)[i] = 0.0f;
    for (int i = tid; i < 3 * PYD * PZD; i += 256) ((float*)P)[i] = 0.0f;
    __syncthreads();

    const uint4* cb = coef + (size_t)b * VOX_;
    const float* pb = pin  + (size_t)b * VOX_;
    float*       ob = pout + (size_t)b * VOX_;

    int oy = tid >> 5;                    // output column of this thread
    int oz = tid & 31;

    for (int x = x_lo - 2; x <= x_hi + 2; ++x) {
        int s0 = (x + 3) % 3;             // slot(x)
        int s1 = (x + 2) % 3;             // slot(x-1)
        int s2 = (x + 1) % 3;             // slot(x-2)

        // ---- A: load phi slice x (zero outside box: Dirichlet) ----
        {
            bool xin = (x >= 0 && x < 128);
            const float* ps = pb + (size_t)(xin ? x : 0) * 16384;
            for (int i = tid; i < PYD * PZD; i += 256) {
                int py = i / PZD, pz = i - py * PZD;
                int y = y0 - 2 + py, z = z0 - 2 + pz;
                float v = 0.0f;
                if (xin && (unsigned)y < 128u && (unsigned)z < 128u)
                    v = ps[y * 128 + z];
                P[s0][i] = v;
            }
        }
        __syncthreads();

        // ---- B: load coef ring for slice k = x-1, stage center, step-1 ----
        int k = x - 1;
        if (k >= x_lo - 1 && k <= x_hi + 1) {
            const uint4* cs = cb + (size_t)((unsigned)k < 128u ? k : 0) * 16384;
            uint4* cf = CF[k & 1];
            for (int i = tid; i < RY * RZ; i += 256) {
                int ry = i / RZ, rz = i - ry * RZ;
                int y = y0 - 1 + ry, z = z0 - 1 + rz;
                float v = 0.0f;
                bool inb = ((unsigned)k < 128u && (unsigned)y < 128u && (unsigned)z < 128u);
                uint4 cu = make_uint4(0u, 0u, 0u, 0u);
                if (inb) {
                    cu = cs[y * 128 + z];
                    const __half2* h = reinterpret_cast<const __half2*>(&cu);
                    float2 a01 = __half22float2(h[0]);
                    float2 a23 = __half22float2(h[1]);
                    float2 a45 = __half22float2(h[2]);
                    float2 a67 = __half22float2(h[3]);
                    int i0 = (ry + 1) * PZD + (rz + 1);
                    v = a01.x * P[s0][i0]        // x+1 neighbor = slice x
                      + a01.y * P[s2][i0]        // x-1 neighbor = slice x-2
                      + a23.x * P[s1][i0 + PZD]
                      + a23.y * P[s1][i0 - PZD]
                      + a45.x * P[s1][i0 + 1]
                      + a45.y * P[s1][i0 - 1]
                      + a67.x;
                }
                if ((unsigned)(ry - 1) < (unsigned)TY && (unsigned)(rz - 1) < (unsigned)TZ)
                    cf[(ry - 1) * TZ + (rz - 1)] = cu;
                S[s1][i] = v;
            }
        }
        __syncthreads();

        // ---- C: compute step-2 output at xo = x-2 from LDS coef, store ----
        int xo = x - 2;
        if (xo >= x_lo && xo <= x_hi) {
            int y = y0 + oy, z = z0 + oz;
            int j0 = (oy + 1) * RZ + (oz + 1);
            // coef center slice xo was staged by B at iter x-1 into slot (xo & 1)
            uint4 cu = CF[xo & 1][oy * TZ + oz];
            const __half2* h = reinterpret_cast<const __half2*>(&cu);
            float2 a01 = __half22float2(h[0]);
            float2 a23 = __half22float2(h[1]);
            float2 a45 = __half22float2(h[2]);
            float2 a67 = __half22float2(h[3]);
            // S: slice xo+1 in s1, slice xo in s2, slice xo-1 in s0
            float out = a01.x * S[s1][j0]
                      + a01.y * S[s0][j0]
                      + a23.x * S[s2][j0 + RZ]
                      + a23.y * S[s2][j0 - RZ]
                      + a45.x * S[s2][j0 + 1]
                      + a45.y * S[s2][j0 - 1]
                      + a67.x;
            ob[(size_t)xo * 16384 + y * 128 + z] = out;
        }
        // no sync needed here: next A writes P only; C reads S/CF only, and the
        // sync after next A orders C(x) before B(x+1)'s S/CF writes.
    }
}

// ---------------- Jacobi sweep v3: 4 z-voxels/thread, fp16 coefs (verified) -
__global__ void jacobi_v3(const uint4* __restrict__ coef,
                          const float* __restrict__ pin,
                          float* __restrict__ pout)
{
    int tid = blockIdx.x * blockDim.x + threadIdx.x;   // 0 .. B*VOX/4-1
    size_t g4 = (size_t)tid * 4;
    int z4 = (int)(g4 & 127);          // 0,4,...,124
    int y  = (int)((g4 >> 7) & 127);
    int x  = (int)((g4 >> 14) & 127);

    float4 pcv = *reinterpret_cast<const float4*>(pin + g4);
    float4 z4v = make_float4(0.f, 0.f, 0.f, 0.f);
    float4 pxpv = (x < 127) ? *reinterpret_cast<const float4*>(pin + g4 + 16384) : z4v;
    float4 pxmv = (x > 0)   ? *reinterpret_cast<const float4*>(pin + g4 - 16384) : z4v;
    float4 pypv = (y < 127) ? *reinterpret_cast<const float4*>(pin + g4 + 128)   : z4v;
    float4 pymv = (y > 0)   ? *reinterpret_cast<const float4*>(pin + g4 - 128)   : z4v;
    float zpE = (z4 < 124) ? pin[g4 + 4] : 0.0f;
    float zmE = (z4 > 0)   ? pin[g4 - 1] : 0.0f;

    float pxp[4] = {pxpv.x, pxpv.y, pxpv.z, pxpv.w};
    float pxm[4] = {pxmv.x, pxmv.y, pxmv.z, pxmv.w};
    float pyp[4] = {pypv.x, pypv.y, pypv.z, pypv.w};
    float pym[4] = {pymv.x, pymv.y, pymv.z, pymv.w};
    float pzp[4] = {pcv.y, pcv.z, pcv.w, zpE};
    float pzm[4] = {zmE, pcv.x, pcv.y, pcv.z};

    float out[4];
#pragma unroll
    for (int j = 0; j < 4; ++j) {
        uint4 cu = coef[g4 + j];
        const __half2* h = reinterpret_cast<const __half2*>(&cu);
        float2 a01 = __half22float2(h[0]);
        float2 a23 = __half22float2(h[1]);
        float2 a45 = __half22float2(h[2]);
        float2 a67 = __half22float2(h[3]);
        out[j] = a01.x * pxp[j] + a01.y * pxm[j]
               + a23.x * pyp[j] + a23.y * pym[j]
               + a45.x * pzp[j] + a45.y * pzm[j]
               + a67.x;
    }
    *reinterpret_cast<float4*>(pout + g4) = make_float4(out[0], out[1], out[2], out[3]);
}

// ---------------- Jacobi sweep v2 (fallback path, verified) ----------------
__global__ void jacobi_v2(const float* __restrict__ eps,
                          const float* __restrict__ q,
                          const float* __restrict__ pin,
                          float* __restrict__ pout)
{
    int bxy = blockIdx.x;
    int b = bxy >> 14;
    int x = (bxy >> 7) & 127;
    int y = bxy & 127;
    int z = threadIdx.x;

    size_t sp = ((size_t)x * 128 + y) * 128 + z;
    size_t g  = (size_t)b * (size_t)VOX_ + sp;
    const float* E = eps + (size_t)b * 4 * (size_t)VOX_;

    float ex = E[sp];
    float ey = E[sp + (size_t)VOX_];
    float ez = E[sp + (size_t)VOX_ * 2];
    float ek = E[sp + (size_t)VOX_ * 3];
    float exm = (x > 0) ? E[sp - 16384]                 : EPS_OUT_C;
    float eym = (y > 0) ? E[sp + (size_t)VOX_ - 128]    : EPS_OUT_C;
    float ezm = (z > 0) ? E[sp + (size_t)VOX_ * 2 - 1]  : EPS_OUT_C;

    float lam = (ek - EPS_IN_C) / (EPS_OUT_C - EPS_IN_C);
    lam = fminf(fmaxf(lam, 0.0f), 1.0f);
    float denom = ex + exm + ey + eym + ez + ezm + KAPPA02_C * lam;

    float pxp = (x < 127) ? pin[g + 16384] : 0.0f;
    float pxm = (x > 0)   ? pin[g - 16384] : 0.0f;
    float pyp = (y < 127) ? pin[g + 128]   : 0.0f;
    float pym = (y > 0)   ? pin[g - 128]   : 0.0f;
    float pzp = (z < 127) ? pin[g + 1]     : 0.0f;
    float pzm = (z > 0)   ? pin[g - 1]     : 0.0f;

    float num = ex * pxp + exm * pxm + ey * pyp + eym * pym
              + ez * pzp + ezm * pzm + FOURPI_C * q[g];
    pout[g] = num / denom;
}

// ---------------- launch ----------------
extern "C" void kernel_launch(void* const* d_in, const int* in_sizes, int n_in,
                              void* d_out, int out_size, void* d_ws, size_t ws_size,
                              hipStream_t stream)
{
    const float* coords    = (const float*)d_in[0];
    const float* params    = (const float*)d_in[1];
    const int*   num_atoms = (const int*)d_in[2];

    float* q   = (float*)d_out;                       // [B][128^3]
    float* eps = q + (size_t)B_ * VOX_;               // [B][4][128^3]
    float* phi = eps + (size_t)B_ * 4 * VOX_;         // [B][128^3]

    hipMemsetAsync(q, 0, (size_t)B_ * VOX_ * sizeof(float), stream);

    scatter_q_kernel<<<(B_ * N_ + 255) / 256, 256, 0, stream>>>(coords, params, num_atoms, q);
    eps_gather_v2<<<B_ * 4096, 512, 0, stream>>>(coords, params, num_atoms, eps);

    size_t coefBytes = (size_t)B_ * VOX_ * sizeof(uint4);              // 134 MB
    size_t need = coefBytes + (size_t)B_ * VOX_ * sizeof(float);       // +33.5 MB

    if (ws_size >= need) {
        uint4* coefA = (uint4*)d_ws;
        float* tmp   = (float*)((char*)d_ws + coefBytes);
        // sweep 1 folded into coef_pack (phi_0 == 0): phi1 -> phi
        coef_pack<<<B_ * 128 * 128, 128, 0, stream>>>(eps, q, coefA, phi);
        const float* cur = phi;
        for (int it = 1; it <= 9; ++it) {           // 9 fused = sweeps 2..19
            float* dst = (it & 1) ? tmp : phi;      // it=9 (odd) -> tmp
            jacobi_f2<<<B_ * 16 * 4 * 8, 256, 0, stream>>>(coefA, cur, dst);
            cur = dst;
        }
        // sweep 20: single v3 sweep tmp -> phi (d_out)
        jacobi_v3<<<(int)(B_ * VOX_ / 4 / 256), 256, 0, stream>>>(coefA, cur, phi);
    } else {
        hipMemsetAsync(phi, 0, (size_t)B_ * VOX_ * sizeof(float), stream);
        float* tmp = (float*)d_ws;
        int jb = B_ * 128 * 128;
        const float* cur = phi;
        for (int it = 1; it <= 20; ++it) {
            float* dst = (it & 1) ? tmp : phi;
            jacobi_v2<<<jb, 128, 0, stream>>>(eps, q, cur, dst);
            cur = dst;
        }
    }
}

// Round 6
// 730.720 us; speedup vs baseline: 2.3951x; 1.2648x over previous
//
#include <hip/hip_runtime.h>
#include <hip/hip_fp16.h>
#include <math.h>

// ---------------- problem constants ----------------
static constexpr int   B_    = 4;
static constexpr int   N_    = 4096;
static constexpr int   BOX_  = 128;
static constexpr long long VOX_ = 1LL * BOX_ * BOX_ * BOX_;   // 2097152
static constexpr float EPS_IN_C  = 6.5f;
static constexpr float EPS_OUT_C = 79.0f;
static constexpr float QCONV_C   = 7046.52f;
static constexpr float KAPPA02_C = 0.8486f;
static constexpr float FOURPI_C  = 12.566370614359172f;

// ---------------- trilinear charge scatter (verified) ----------
__global__ void scatter_q_kernel(const float* __restrict__ coords,
                                 const float* __restrict__ params,
                                 const int*   __restrict__ num_atoms,
                                 float* __restrict__ q)
{
    int a = blockIdx.x * blockDim.x + threadIdx.x;
    if (a >= B_ * N_) return;
    int b = a >> 12;
    int n = a & (N_ - 1);
    if (n >= num_atoms[b]) return;

    float cx = coords[3 * a + 0];
    float cy = coords[3 * a + 1];
    float cz = coords[3 * a + 2];
    float chg = params[2 * a + 0] * QCONV_C;

    int ix0 = (int)floorf(cx), iy0 = (int)floorf(cy), iz0 = (int)floorf(cz);
    float fx = cx - (float)ix0, fy = cy - (float)iy0, fz = cz - (float)iz0;
    float wx[2] = {1.0f - fx, fx};
    float wy[2] = {1.0f - fy, fy};
    float wz[2] = {1.0f - fz, fz};

    float* qb = q + (long long)b * VOX_;
#pragma unroll
    for (int dx = 0; dx < 2; ++dx) {
        int ix = ix0 + dx;
        if ((unsigned)ix >= 128u) continue;
#pragma unroll
        for (int dy = 0; dy < 2; ++dy) {
            int iy = iy0 + dy;
            if ((unsigned)iy >= 128u) continue;
#pragma unroll
            for (int dz = 0; dz < 2; ++dz) {
                int iz = iz0 + dz;
                if ((unsigned)iz >= 128u) continue;
                atomicAdd(&qb[((long long)ix * 128 + iy) * 128 + iz],
                          chg * wx[dx] * wy[dy] * wz[dz]);
            }
        }
    }
}

// ---------------- eps gather v2: separable per-axis weights in LDS ----------
// Weight semantics identical to verified round-5 axis_d2 (JAX wrap on negatives).
#define CAND_CAP 512
#define CHUNK 32

__global__ void eps_gather_v2(const float* __restrict__ coords,
                              const float* __restrict__ params,
                              const int*   __restrict__ num_atoms,
                              float* __restrict__ eps)   // [B][4][128^3]
{
    int tileId = blockIdx.x;            // B * 4096 tiles
    int b  = tileId >> 12;
    int t  = tileId & 4095;
    int tx = ((t >> 8) & 15) << 3;
    int ty = ((t >> 4) & 15) << 3;
    int tz = (t & 15) << 3;

    __shared__ float sx[CAND_CAP], sy[CAND_CAP], sz[CAND_CAP], sr[CAND_CAP];
    __shared__ float wts[CHUNK][9][8];   // [atom][axis*3+variant][tile pos]
    __shared__ int s_cnt;
    if (threadIdx.x == 0) s_cnt = 0;
    __syncthreads();

    int na = num_atoms[b];
    const float* cb = coords + (size_t)b * N_ * 3;
    const float* pb = params + (size_t)b * N_ * 2;

    float lox = (float)tx - 6.0f, hix = (float)tx + 14.0f;
    float loy = (float)ty - 6.0f, hiy = (float)ty + 14.0f;
    float loz = (float)tz - 6.0f, hiz = (float)tz + 14.0f;
    bool wx_ = (tx == 120), wy_ = (ty == 120), wz_ = (tz == 120);
    for (int n = threadIdx.x; n < na; n += blockDim.x) {
        float cx = cb[3 * n], cy = cb[3 * n + 1], cz = cb[3 * n + 2];
        bool okx = (cx >= lox && cx < hix) || (wx_ && cx < 6.0f);
        bool oky = (cy >= loy && cy < hiy) || (wy_ && cy < 6.0f);
        bool okz = (cz >= loz && cz < hiz) || (wz_ && cz < 6.0f);
        if (okx && oky && okz) {
            int slot = atomicAdd(&s_cnt, 1);
            if (slot < CAND_CAP) {
                sx[slot] = cx; sy[slot] = cy; sz[slot] = cz;
                sr[slot] = pb[2 * n + 1];
            }
        }
    }
    __syncthreads();
    int cnt = min(s_cnt, CAND_CAP);

    int lz = threadIdx.x & 7;
    int ly = (threadIdx.x >> 3) & 7;
    int lx = threadIdx.x >> 6;

    float r0 = 0.0f, r1 = 0.0f, r2 = 0.0f, r3 = 0.0f;

    for (int k0 = 0; k0 < cnt; k0 += CHUNK) {
        int nC = min(CHUNK, cnt - k0);
        __syncthreads();   // protect wts reuse across chunk iterations
        // Phase A: fill per-atom separable axis weights (72 expf per atom)
        for (int w = threadIdx.x; w < nC * 72; w += 512) {
            int ka  = w / 72;
            int rem = w - ka * 72;
            int vi  = rem >> 3;        // 0..8 = axis*3 + variant
            int pos = rem & 7;
            int axis = vi / 3, var = vi - axis * 3;
            int k = k0 + ka;
            float c     = (axis == 0) ? sx[k] : (axis == 1) ? sy[k] : sz[k];
            int   torig = (axis == 0) ? tx    : (axis == 1) ? ty    : tz;
            float r = sr[k];
            float sig = (var == 2) ? (r + 1.0f) * 0.5f : (r + 1.4f) * 0.5f;
            float off = (var == 0) ? 0.0f : 0.5f;
            float inv2s2 = 1.0f / (2.0f * sig * sig);
            int i = torig + pos;
            int base = (int)floorf(c - off) - 4;    // window [base, base+8]
            float wv = 0.0f;
            if ((unsigned)(i - base) <= 8u) {
                float d = (float)i + off - c;
                wv = expf(-d * d * inv2s2);
            } else if ((unsigned)(i - 128 - base) <= 8u) {   // JAX negative wrap
                float d = (float)(i - 128) + off - c;
                wv = expf(-d * d * inv2s2);
            }
            wts[ka][vi][pos] = wv;
        }
        __syncthreads();
        // Phase B: accumulate channels from separable products
        for (int ka = 0; ka < nC; ++ka) {
            float xE0 = wts[ka][0][lx], xE5 = wts[ka][1][lx], xI5 = wts[ka][2][lx];
            float yE0 = wts[ka][3][ly], yE5 = wts[ka][4][ly], yI5 = wts[ka][5][ly];
            float zE0 = wts[ka][6][lz], zE5 = wts[ka][7][lz], zI5 = wts[ka][8][lz];
            r0 += xE5 * yE0 * zE0;     // c0: off (.5,0,0)  sigE
            r1 += xE0 * yE5 * zE0;     // c1: off (0,.5,0)  sigE
            r2 += xE0 * yE0 * zE5;     // c2: off (0,0,.5)  sigE
            r3 += xI5 * yI5 * zI5;     // c3: off (.5,.5,.5) sigI
        }
    }

    int ix = tx + lx, iy = ty + ly, iz = tz + lz;
    size_t sp = ((size_t)ix * 128 + iy) * 128 + iz;
    float* eb = eps + (size_t)b * 4 * VOX_;
    eb[sp]                    = EPS_OUT_C + (EPS_IN_C - EPS_OUT_C) * fminf(fmaxf(r0, 0.0f), 1.0f);
    eb[sp + (size_t)VOX_]     = EPS_OUT_C + (EPS_IN_C - EPS_OUT_C) * fminf(fmaxf(r1, 0.0f), 1.0f);
    eb[sp + (size_t)VOX_ * 2] = EPS_OUT_C + (EPS_IN_C - EPS_OUT_C) * fminf(fmaxf(r2, 0.0f), 1.0f);
    eb[sp + (size_t)VOX_ * 3] = EPS_OUT_C + (EPS_IN_C - EPS_OUT_C) * fminf(fmaxf(r3, 0.0f), 1.0f);
}

// ---------------- coefficient pack + fold of Jacobi sweep 1 -----------------
__global__ void coef_pack(const float* __restrict__ eps,
                          const float* __restrict__ q,
                          uint4* __restrict__ coef,
                          float* __restrict__ phi1)
{
    int bxy = blockIdx.x;
    int b = bxy >> 14;
    int x = (bxy >> 7) & 127;
    int y = bxy & 127;
    int z = threadIdx.x;

    size_t sp = ((size_t)x * 128 + y) * 128 + z;
    size_t g  = (size_t)b * (size_t)VOX_ + sp;
    const float* E = eps + (size_t)b * 4 * (size_t)VOX_;

    float ex = E[sp];
    float ey = E[sp + (size_t)VOX_];
    float ez = E[sp + (size_t)VOX_ * 2];
    float ek = E[sp + (size_t)VOX_ * 3];
    float exm = (x > 0) ? E[sp - 16384]                 : EPS_OUT_C;
    float eym = (y > 0) ? E[sp + (size_t)VOX_ - 128]    : EPS_OUT_C;
    float ezm = (z > 0) ? E[sp + (size_t)VOX_ * 2 - 1]  : EPS_OUT_C;

    float lam = (ek - EPS_IN_C) / (EPS_OUT_C - EPS_IN_C);
    lam = fminf(fmaxf(lam, 0.0f), 1.0f);
    float denom = ex + exm + ey + eym + ez + ezm + KAPPA02_C * lam;
    float rcp = 1.0f / denom;

    __half2 h01 = __floats2half2_rn(ex  * rcp, exm * rcp);
    __half2 h23 = __floats2half2_rn(ey  * rcp, eym * rcp);
    __half2 h45 = __floats2half2_rn(ez  * rcp, ezm * rcp);
    __half2 h67 = __floats2half2_rn(FOURPI_C * q[g] * rcp, 0.0f);
    uint4 u;
    u.x = *(unsigned int*)&h01;
    u.y = *(unsigned int*)&h23;
    u.z = *(unsigned int*)&h45;
    u.w = *(unsigned int*)&h67;
    coef[g] = u;
    phi1[g] = __half22float2(h67).x;   // sweep-1 result (phi_0 == 0)
}

// ---------------- fused 2-step Jacobi, prefetched (T14) ---------------------
// Two sweeps per launch. All global loads are issued one x-iteration ahead
// into registers; raw s_barrier + lgkmcnt(0) keeps them in flight across
// barriers (plain __syncthreads would drain vmcnt). Coef lives in registers:
// each thread owns its C-center ring entry (+ one halo entry for tid<84).
// Arithmetic values/order identical to round-5 f2 -> bitwise-identical output.
#define TY 8
#define TZ 32
#define RY (TY + 2)    // 10
#define RZ (TZ + 2)    // 34
#define PYD (TY + 4)   // 12
#define PZD (TZ + 4)   // 36
#define SEG 16         // 2048 blocks = 8/CU

__global__ __launch_bounds__(256)
void jacobi_f2p(const uint4* __restrict__ coef,
                const float* __restrict__ pin,
                float* __restrict__ pout)
{
    int bid = blockIdx.x;                 // 2048 blocks
    int xs = bid & 7;
    int zt = (bid >> 3) & 3;
    int yt = (bid >> 5) & 15;
    int b  = bid >> 9;
    int x_lo = xs * SEG, x_hi = x_lo + SEG - 1;
    int y0 = yt * TY, z0 = zt * TZ;

    __shared__ float P[3][PYD * PZD];     // phi_in slices x, x-1, x-2
    __shared__ float S[3][RY * RZ];       // step-1 phi slices

    int tid = threadIdx.x;
    int oy = tid >> 5, oz = tid & 31;

    const uint4* cb = coef + (size_t)b * VOX_;
    const float* pb = pin  + (size_t)b * VOX_;
    float*       ob = pout + (size_t)b * VOX_;

    // ---- static per-thread geometry ----
    // coef ring entry 1: this thread's C-center cell (always in-bounds y/z)
    int e1_i  = (oy + 1) * RZ + (oz + 1);
    int g1y = y0 + oy, g1z = z0 + oz;
    int e1_off = g1y * 128 + g1z;
    int e1_p0 = (oy + 2) * PZD + (oz + 2);        // P index for ring (oy+1,oz+1)
    // coef ring entry 2: halo cell, threads 0..83
    bool has2 = (tid < 84);
    int e2_ry = 0, e2_rz = 0;
    if (tid < 34)      { e2_ry = 0;      e2_rz = tid; }
    else if (tid < 68) { e2_ry = RY - 1; e2_rz = tid - 34; }
    else if (tid < 84) { int t2 = tid - 68; e2_ry = 1 + (t2 >> 1); e2_rz = (t2 & 1) * (RZ - 1); }
    int e2_i = e2_ry * RZ + e2_rz;
    int g2y = y0 - 1 + e2_ry, g2z = z0 - 1 + e2_rz;
    bool e2_ok = ((unsigned)g2y < 128u) && ((unsigned)g2z < 128u);
    int e2_off = min(max(g2y, 0), 127) * 128 + min(max(g2z, 0), 127);
    int e2_p0 = (e2_ry + 1) * PZD + (e2_rz + 1);
    // phi tile entries: j = tid and tid+256 (tid<176)
    int p1_py = tid / PZD, p1_pz = tid - p1_py * PZD;
    int p1y = y0 - 2 + p1_py, p1z = z0 - 2 + p1_pz;
    bool p1_ok = ((unsigned)p1y < 128u) && ((unsigned)p1z < 128u);
    int p1_off = min(max(p1y, 0), 127) * 128 + min(max(p1z, 0), 127);
    int p2i = tid + 256;
    bool hasP2 = (p2i < PYD * PZD);
    int p2_py = p2i / PZD, p2_pz = p2i - p2_py * PZD;
    int p2y = y0 - 2 + p2_py, p2z = z0 - 2 + p2_pz;
    bool p2_ok = hasP2 && ((unsigned)p2y < 128u) && ((unsigned)p2z < 128u);
    int p2_off = min(max(p2y, 0), 127) * 128 + min(max(p2z, 0), 127);

    // ---- prologue: prefetch phi(x_lo-2) ----
    {
        int xc = min(max(x_lo - 2, 0), 127);
        // issued here; consumed in first W below
    }
    const float* ps0 = pb + (size_t)min(max(x_lo - 2, 0), 127) * 16384;
    float pfA = ps0[p1_off];
    float pfB = hasP2 ? ps0[p2_off] : 0.0f;
    uint4 cf1 = make_uint4(0u, 0u, 0u, 0u);
    uint4 cf2 = make_uint4(0u, 0u, 0u, 0u);
    uint4 hold = make_uint4(0u, 0u, 0u, 0u);
    uint4 cnew = make_uint4(0u, 0u, 0u, 0u);

    for (int x = x_lo - 2; x <= x_hi + 2; ++x) {
        int s0 = (x + 3) % 3;             // slot(x)
        int s1 = (x + 2) % 3;             // slot(x-1)
        int s2 = (x + 1) % 3;             // slot(x-2)
        bool xin = (x >= 0 && x < 128);

        // ---- W: commit prefetched phi(x) to P[s0] ----
        P[s0][tid] = (xin && p1_ok) ? pfA : 0.0f;
        if (hasP2) P[s0][p2i] = (xin && p2_ok) ? pfB : 0.0f;
        asm volatile("s_waitcnt lgkmcnt(0)" ::: "memory");
        __builtin_amdgcn_s_barrier();

        // ---- I: issue phi(x+1) prefetch (consumed next W) ----
        if (x < x_hi + 2) {
            const float* ps = pb + (size_t)min(max(x + 1, 0), 127) * 16384;
            pfA = ps[p1_off];
            if (hasP2) pfB = ps[p2_off];
        }

        // ---- B: compute S1(x-1) from coef regs + P ----
        if (x >= x_lo) {
            int k = x - 1;
            bool kin = ((unsigned)k < 128u);
            // entry 1 (center)
            {
                float v = 0.0f;
                if (kin) {
                    const __half2* h = reinterpret_cast<const __half2*>(&cf1);
                    float2 a01 = __half22float2(h[0]);
                    float2 a23 = __half22float2(h[1]);
                    float2 a45 = __half22float2(h[2]);
                    float2 a67 = __half22float2(h[3]);
                    v = a01.x * P[s0][e1_p0]
                      + a01.y * P[s2][e1_p0]
                      + a23.x * P[s1][e1_p0 + PZD]
                      + a23.y * P[s1][e1_p0 - PZD]
                      + a45.x * P[s1][e1_p0 + 1]
                      + a45.y * P[s1][e1_p0 - 1]
                      + a67.x;
                }
                S[s1][e1_i] = v;
                cnew = cf1;                    // center coef for C(x+1)
            }
            // entry 2 (halo)
            if (has2) {
                float v = 0.0f;
                if (kin && e2_ok) {
                    const __half2* h = reinterpret_cast<const __half2*>(&cf2);
                    float2 a01 = __half22float2(h[0]);
                    float2 a23 = __half22float2(h[1]);
                    float2 a45 = __half22float2(h[2]);
                    float2 a67 = __half22float2(h[3]);
                    v = a01.x * P[s0][e2_p0]
                      + a01.y * P[s2][e2_p0]
                      + a23.x * P[s1][e2_p0 + PZD]
                      + a23.y * P[s1][e2_p0 - PZD]
                      + a45.x * P[s1][e2_p0 + 1]
                      + a45.y * P[s1][e2_p0 - 1]
                      + a67.x;
                }
                S[s1][e2_i] = v;
            }
        }
        // issue coef slice x prefetch (consumed at B(x+1))
        if (x >= x_lo - 1 && x <= x_hi + 1) {
            const uint4* cs = cb + (size_t)min(max(x, 0), 127) * 16384;
            cf1 = cs[e1_off];
            if (has2) cf2 = cs[e2_off];
        }
        asm volatile("s_waitcnt lgkmcnt(0)" ::: "memory");
        __builtin_amdgcn_s_barrier();

        // ---- C: output xo = x-2 from reg coef + S ----
        int xo = x - 2;
        if (xo >= x_lo) {
            const __half2* h = reinterpret_cast<const __half2*>(&hold);
            float2 a01 = __half22float2(h[0]);
            float2 a23 = __half22float2(h[1]);
            float2 a45 = __half22float2(h[2]);
            float2 a67 = __half22float2(h[3]);
            int j0 = e1_i;
            float out = a01.x * S[s1][j0]
                      + a01.y * S[s0][j0]
                      + a23.x * S[s2][j0 + RZ]
                      + a23.y * S[s2][j0 - RZ]
                      + a45.x * S[s2][j0 + 1]
                      + a45.y * S[s2][j0 - 1]
                      + a67.x;
            ob[(size_t)xo * 16384 + e1_off] = out;
        }
        hold = cnew;
        // no barrier needed here: C's S-reads complete in-phase (compiler
        // waits before use); next W writes P only (disjoint from S).
    }
}

// ---------------- Jacobi sweep v3: 4 z-voxels/thread, fp16 coefs (verified) -
__global__ void jacobi_v3(const uint4* __restrict__ coef,
                          const float* __restrict__ pin,
                          float* __restrict__ pout)
{
    int tid = blockIdx.x * blockDim.x + threadIdx.x;   // 0 .. B*VOX/4-1
    size_t g4 = (size_t)tid * 4;
    int z4 = (int)(g4 & 127);          // 0,4,...,124
    int y  = (int)((g4 >> 7) & 127);
    int x  = (int)((g4 >> 14) & 127);

    float4 pcv = *reinterpret_cast<const float4*>(pin + g4);
    float4 z4v = make_float4(0.f, 0.f, 0.f, 0.f);
    float4 pxpv = (x < 127) ? *reinterpret_cast<const float4*>(pin + g4 + 16384) : z4v;
    float4 pxmv = (x > 0)   ? *reinterpret_cast<const float4*>(pin + g4 - 16384) : z4v;
    float4 pypv = (y < 127) ? *reinterpret_cast<const float4*>(pin + g4 + 128)   : z4v;
    float4 pymv = (y > 0)   ? *reinterpret_cast<const float4*>(pin + g4 - 128)   : z4v;
    float zpE = (z4 < 124) ? pin[g4 + 4] : 0.0f;
    float zmE = (z4 > 0)   ? pin[g4 - 1] : 0.0f;

    float pxp[4] = {pxpv.x, pxpv.y, pxpv.z, pxpv.w};
    float pxm[4] = {pxmv.x, pxmv.y, pxmv.z, pxmv.w};
    float pyp[4] = {pypv.x, pypv.y, pypv.z, pypv.w};
    float pym[4] = {pymv.x, pymv.y, pymv.z, pymv.w};
    float pzp[4] = {pcv.y, pcv.z, pcv.w, zpE};
    float pzm[4] = {zmE, pcv.x, pcv.y, pcv.z};

    float out[4];
#pragma unroll
    for (int j = 0; j < 4; ++j) {
        uint4 cu = coef[g4 + j];
        const __half2* h = reinterpret_cast<const __half2*>(&cu);
        float2 a01 = __half22float2(h[0]);
        float2 a23 = __half22float2(h[1]);
        float2 a45 = __half22float2(h[2]);
        float2 a67 = __half22float2(h[3]);
        out[j] = a01.x * pxp[j] + a01.y * pxm[j]
               + a23.x * pyp[j] + a23.y * pym[j]
               + a45.x * pzp[j] + a45.y * pzm[j]
               + a67.x;
    }
    *reinterpret_cast<float4*>(pout + g4) = make_float4(out[0], out[1], out[2], out[3]);
}

// ---------------- Jacobi sweep v2 (fallback path, verified) ----------------
__global__ void jacobi_v2(const float* __restrict__ eps,
                          const float* __restrict__ q,
                          const float* __restrict__ pin,
                          float* __restrict__ pout)
{
    int bxy = blockIdx.x;
    int b = bxy >> 14;
    int x = (bxy >> 7) & 127;
    int y = bxy & 127;
    int z = threadIdx.x;

    size_t sp = ((size_t)x * 128 + y) * 128 + z;
    size_t g  = (size_t)b * (size_t)VOX_ + sp;
    const float* E = eps + (size_t)b * 4 * (size_t)VOX_;

    float ex = E[sp];
    float ey = E[sp + (size_t)VOX_];
    float ez = E[sp + (size_t)VOX_ * 2];
    float ek = E[sp + (size_t)VOX_ * 3];
    float exm = (x > 0) ? E[sp - 16384]                 : EPS_OUT_C;
    float eym = (y > 0) ? E[sp + (size_t)VOX_ - 128]    : EPS_OUT_C;
    float ezm = (z > 0) ? E[sp + (size_t)VOX_ * 2 - 1]  : EPS_OUT_C;

    float lam = (ek - EPS_IN_C) / (EPS_OUT_C - EPS_IN_C);
    lam = fminf(fmaxf(lam, 0.0f), 1.0f);
    float denom = ex + exm + ey + eym + ez + ezm + KAPPA02_C * lam;

    float pxp = (x < 127) ? pin[g + 16384] : 0.0f;
    float pxm = (x > 0)   ? pin[g - 16384] : 0.0f;
    float pyp = (y < 127) ? pin[g + 128]   : 0.0f;
    float pym = (y > 0)   ? pin[g - 128]   : 0.0f;
    float pzp = (z < 127) ? pin[g + 1]     : 0.0f;
    float pzm = (z > 0)   ? pin[g - 1]     : 0.0f;

    float num = ex * pxp + exm * pxm + ey * pyp + eym * pym
              + ez * pzp + ezm * pzm + FOURPI_C * q[g];
    pout[g] = num / denom;
}

// ---------------- launch ----------------
extern "C" void kernel_launch(void* const* d_in, const int* in_sizes, int n_in,
                              void* d_out, int out_size, void* d_ws, size_t ws_size,
                              hipStream_t stream)
{
    const float* coords    = (const float*)d_in[0];
    const float* params    = (const float*)d_in[1];
    const int*   num_atoms = (const int*)d_in[2];

    float* q   = (float*)d_out;                       // [B][128^3]
    float* eps = q + (size_t)B_ * VOX_;               // [B][4][128^3]
    float* phi = eps + (size_t)B_ * 4 * VOX_;         // [B][128^3]

    hipMemsetAsync(q, 0, (size_t)B_ * VOX_ * sizeof(float), stream);

    scatter_q_kernel<<<(B_ * N_ + 255) / 256, 256, 0, stream>>>(coords, params, num_atoms, q);
    eps_gather_v2<<<B_ * 4096, 512, 0, stream>>>(coords, params, num_atoms, eps);

    size_t coefBytes = (size_t)B_ * VOX_ * sizeof(uint4);              // 134 MB
    size_t need = coefBytes + (size_t)B_ * VOX_ * sizeof(float);       // +33.5 MB

    if (ws_size >= need) {
        uint4* coefA = (uint4*)d_ws;
        float* tmp   = (float*)((char*)d_ws + coefBytes);
        // sweep 1 folded into coef_pack (phi_0 == 0): phi1 -> phi
        coef_pack<<<B_ * 128 * 128, 128, 0, stream>>>(eps, q, coefA, phi);
        const float* cur = phi;
        for (int it = 1; it <= 9; ++it) {           // 9 fused = sweeps 2..19
            float* dst = (it & 1) ? tmp : phi;      // it=9 (odd) -> tmp
            jacobi_f2p<<<B_ * 16 * 4 * 8, 256, 0, stream>>>(coefA, cur, dst);
            cur = dst;
        }
        // sweep 20: single v3 sweep tmp -> phi (d_out)
        jacobi_v3<<<(int)(B_ * VOX_ / 4 / 256), 256, 0, stream>>>(coefA, cur, phi);
    } else {
        hipMemsetAsync(phi, 0, (size_t)B_ * VOX_ * sizeof(float), stream);
        float* tmp = (float*)d_ws;
        int jb = B_ * 128 * 128;
        const float* cur = phi;
        for (int it = 1; it <= 20; ++it) {
            float* dst = (it & 1) ? tmp : phi;
            jacobi_v2<<<jb, 128, 0, stream>>>(eps, q, cur, dst);
            cur = dst;
        }
    }
}

// Round 7
// 721.020 us; speedup vs baseline: 2.4273x; 1.0135x over previous
//
#include <hip/hip_runtime.h>
#include <hip/hip_fp16.h>
#include <math.h>

// ---------------- problem constants ----------------
static constexpr int   B_    = 4;
static constexpr int   N_    = 4096;
static constexpr int   BOX_  = 128;
static constexpr long long VOX_ = 1LL * BOX_ * BOX_ * BOX_;   // 2097152
static constexpr float EPS_IN_C  = 6.5f;
static constexpr float EPS_OUT_C = 79.0f;
static constexpr float QCONV_C   = 7046.52f;
static constexpr float KAPPA02_C = 0.8486f;
static constexpr float FOURPI_C  = 12.566370614359172f;

// ---------------- trilinear charge scatter (verified) ----------
__global__ void scatter_q_kernel(const float* __restrict__ coords,
                                 const float* __restrict__ params,
                                 const int*   __restrict__ num_atoms,
                                 float* __restrict__ q)
{
    int a = blockIdx.x * blockDim.x + threadIdx.x;
    if (a >= B_ * N_) return;
    int b = a >> 12;
    int n = a & (N_ - 1);
    if (n >= num_atoms[b]) return;

    float cx = coords[3 * a + 0];
    float cy = coords[3 * a + 1];
    float cz = coords[3 * a + 2];
    float chg = params[2 * a + 0] * QCONV_C;

    int ix0 = (int)floorf(cx), iy0 = (int)floorf(cy), iz0 = (int)floorf(cz);
    float fx = cx - (float)ix0, fy = cy - (float)iy0, fz = cz - (float)iz0;
    float wx[2] = {1.0f - fx, fx};
    float wy[2] = {1.0f - fy, fy};
    float wz[2] = {1.0f - fz, fz};

    float* qb = q + (long long)b * VOX_;
#pragma unroll
    for (int dx = 0; dx < 2; ++dx) {
        int ix = ix0 + dx;
        if ((unsigned)ix >= 128u) continue;
#pragma unroll
        for (int dy = 0; dy < 2; ++dy) {
            int iy = iy0 + dy;
            if ((unsigned)iy >= 128u) continue;
#pragma unroll
            for (int dz = 0; dz < 2; ++dz) {
                int iz = iz0 + dz;
                if ((unsigned)iz >= 128u) continue;
                atomicAdd(&qb[((long long)ix * 128 + iy) * 128 + iz],
                          chg * wx[dx] * wy[dy] * wz[dz]);
            }
        }
    }
}

// ---------------- eps gather v2: separable per-axis weights in LDS ----------
// Weight semantics identical to verified round-5 axis_d2 (JAX wrap on negatives).
// Round-7: candidate window tightened to EXACT Gaussian support overlap:
//   support i in [floor(c-off)-4, floor(c-off)+4]; overlap with [t, t+8)
//   <=> c in [t-4+off, t+12+off); union over off in {0,0.5} = [t-4, t+12.5).
//   wrap (t=120): need floor(c-off) <= 3 => c < 4.5.
// Atoms outside these bounds produced exactly-zero weights before (r += 0),
// so the output is unchanged; Phase-B cost drops ~1.8x.
#define CAND_CAP 512
#define CHUNK 32

__global__ void eps_gather_v2(const float* __restrict__ coords,
                              const float* __restrict__ params,
                              const int*   __restrict__ num_atoms,
                              float* __restrict__ eps)   // [B][4][128^3]
{
    int tileId = blockIdx.x;            // B * 4096 tiles
    int b  = tileId >> 12;
    int t  = tileId & 4095;
    int tx = ((t >> 8) & 15) << 3;
    int ty = ((t >> 4) & 15) << 3;
    int tz = (t & 15) << 3;

    __shared__ float sx[CAND_CAP], sy[CAND_CAP], sz[CAND_CAP], sr[CAND_CAP];
    __shared__ float wts[CHUNK][9][8];   // [atom][axis*3+variant][tile pos]
    __shared__ int s_cnt;
    if (threadIdx.x == 0) s_cnt = 0;
    __syncthreads();

    int na = num_atoms[b];
    const float* cb = coords + (size_t)b * N_ * 3;
    const float* pb = params + (size_t)b * N_ * 2;

    float lox = (float)tx - 4.0f, hix = (float)tx + 12.5f;
    float loy = (float)ty - 4.0f, hiy = (float)ty + 12.5f;
    float loz = (float)tz - 4.0f, hiz = (float)tz + 12.5f;
    bool wx_ = (tx == 120), wy_ = (ty == 120), wz_ = (tz == 120);
    for (int n = threadIdx.x; n < na; n += blockDim.x) {
        float cx = cb[3 * n], cy = cb[3 * n + 1], cz = cb[3 * n + 2];
        bool okx = (cx >= lox && cx < hix) || (wx_ && cx < 4.5f);
        bool oky = (cy >= loy && cy < hiy) || (wy_ && cy < 4.5f);
        bool okz = (cz >= loz && cz < hiz) || (wz_ && cz < 4.5f);
        if (okx && oky && okz) {
            int slot = atomicAdd(&s_cnt, 1);
            if (slot < CAND_CAP) {
                sx[slot] = cx; sy[slot] = cy; sz[slot] = cz;
                sr[slot] = pb[2 * n + 1];
            }
        }
    }
    __syncthreads();
    int cnt = min(s_cnt, CAND_CAP);

    int lz = threadIdx.x & 7;
    int ly = (threadIdx.x >> 3) & 7;
    int lx = threadIdx.x >> 6;

    float r0 = 0.0f, r1 = 0.0f, r2 = 0.0f, r3 = 0.0f;

    for (int k0 = 0; k0 < cnt; k0 += CHUNK) {
        int nC = min(CHUNK, cnt - k0);
        __syncthreads();   // protect wts reuse across chunk iterations
        // Phase A: fill per-atom separable axis weights (72 expf per atom)
        for (int w = threadIdx.x; w < nC * 72; w += 512) {
            int ka  = w / 72;
            int rem = w - ka * 72;
            int vi  = rem >> 3;        // 0..8 = axis*3 + variant
            int pos = rem & 7;
            int axis = vi / 3, var = vi - axis * 3;
            int k = k0 + ka;
            float c     = (axis == 0) ? sx[k] : (axis == 1) ? sy[k] : sz[k];
            int   torig = (axis == 0) ? tx    : (axis == 1) ? ty    : tz;
            float r = sr[k];
            float sig = (var == 2) ? (r + 1.0f) * 0.5f : (r + 1.4f) * 0.5f;
            float off = (var == 0) ? 0.0f : 0.5f;
            float inv2s2 = 1.0f / (2.0f * sig * sig);
            int i = torig + pos;
            int base = (int)floorf(c - off) - 4;    // window [base, base+8]
            float wv = 0.0f;
            if ((unsigned)(i - base) <= 8u) {
                float d = (float)i + off - c;
                wv = expf(-d * d * inv2s2);
            } else if ((unsigned)(i - 128 - base) <= 8u) {   // JAX negative wrap
                float d = (float)(i - 128) + off - c;
                wv = expf(-d * d * inv2s2);
            }
            wts[ka][vi][pos] = wv;
        }
        __syncthreads();
        // Phase B: accumulate channels from separable products
        for (int ka = 0; ka < nC; ++ka) {
            float xE0 = wts[ka][0][lx], xE5 = wts[ka][1][lx], xI5 = wts[ka][2][lx];
            float yE0 = wts[ka][3][ly], yE5 = wts[ka][4][ly], yI5 = wts[ka][5][ly];
            float zE0 = wts[ka][6][lz], zE5 = wts[ka][7][lz], zI5 = wts[ka][8][lz];
            r0 += xE5 * yE0 * zE0;     // c0: off (.5,0,0)  sigE
            r1 += xE0 * yE5 * zE0;     // c1: off (0,.5,0)  sigE
            r2 += xE0 * yE0 * zE5;     // c2: off (0,0,.5)  sigE
            r3 += xI5 * yI5 * zI5;     // c3: off (.5,.5,.5) sigI
        }
    }

    int ix = tx + lx, iy = ty + ly, iz = tz + lz;
    size_t sp = ((size_t)ix * 128 + iy) * 128 + iz;
    float* eb = eps + (size_t)b * 4 * VOX_;
    eb[sp]                    = EPS_OUT_C + (EPS_IN_C - EPS_OUT_C) * fminf(fmaxf(r0, 0.0f), 1.0f);
    eb[sp + (size_t)VOX_]     = EPS_OUT_C + (EPS_IN_C - EPS_OUT_C) * fminf(fmaxf(r1, 0.0f), 1.0f);
    eb[sp + (size_t)VOX_ * 2] = EPS_OUT_C + (EPS_IN_C - EPS_OUT_C) * fminf(fmaxf(r2, 0.0f), 1.0f);
    eb[sp + (size_t)VOX_ * 3] = EPS_OUT_C + (EPS_IN_C - EPS_OUT_C) * fminf(fmaxf(r3, 0.0f), 1.0f);
}

// ---------------- coefficient pack v4: 4 z-voxels/thread, vectorized --------
// Same per-voxel formulas/rounding as verified coef_pack -> bitwise identical.
// Folds Jacobi sweep 1 (phi_0 == 0): phi1 = float(half(4*pi*q*rcp)).
__global__ void coef_pack4(const float* __restrict__ eps,
                           const float* __restrict__ q,
                           uint4* __restrict__ coef,
                           float* __restrict__ phi1)
{
    int tid = blockIdx.x * blockDim.x + threadIdx.x;   // 0 .. B*VOX/4-1
    size_t g4 = (size_t)tid * 4;
    int b  = (int)(g4 >> 21);
    size_t sp = g4 & (size_t)(VOX_ - 1);
    int x  = (int)(sp >> 14);
    int y  = (int)((sp >> 7) & 127);
    int z4 = (int)(sp & 127);          // 0,4,...,124

    const float* E = eps + (size_t)b * 4 * (size_t)VOX_;
    float4 ex4 = *reinterpret_cast<const float4*>(E + sp);
    float4 ey4 = *reinterpret_cast<const float4*>(E + sp + (size_t)VOX_);
    float4 ez4 = *reinterpret_cast<const float4*>(E + sp + (size_t)VOX_ * 2);
    float4 ek4 = *reinterpret_cast<const float4*>(E + sp + (size_t)VOX_ * 3);
    float4 eo  = make_float4(EPS_OUT_C, EPS_OUT_C, EPS_OUT_C, EPS_OUT_C);
    float4 exm4 = (x > 0) ? *reinterpret_cast<const float4*>(E + sp - 16384) : eo;
    float4 eym4 = (y > 0) ? *reinterpret_cast<const float4*>(E + sp + (size_t)VOX_ - 128) : eo;
    float ezm0  = (z4 > 0) ? E[sp + (size_t)VOX_ * 2 - 1] : EPS_OUT_C;
    float4 q4  = *reinterpret_cast<const float4*>(q + g4);

    float exA[4]  = {ex4.x, ex4.y, ex4.z, ex4.w};
    float eyA[4]  = {ey4.x, ey4.y, ey4.z, ey4.w};
    float ezA[4]  = {ez4.x, ez4.y, ez4.z, ez4.w};
    float ekA[4]  = {ek4.x, ek4.y, ek4.z, ek4.w};
    float exmA[4] = {exm4.x, exm4.y, exm4.z, exm4.w};
    float eymA[4] = {eym4.x, eym4.y, eym4.z, eym4.w};
    float ezmA[4] = {ezm0, ez4.x, ez4.y, ez4.z};
    float qA[4]   = {q4.x, q4.y, q4.z, q4.w};

    float ph[4];
#pragma unroll
    for (int j = 0; j < 4; ++j) {
        float lam = (ekA[j] - EPS_IN_C) / (EPS_OUT_C - EPS_IN_C);
        lam = fminf(fmaxf(lam, 0.0f), 1.0f);
        float denom = exA[j] + exmA[j] + eyA[j] + eymA[j] + ezA[j] + ezmA[j]
                    + KAPPA02_C * lam;
        float rcp = 1.0f / denom;

        __half2 h01 = __floats2half2_rn(exA[j] * rcp, exmA[j] * rcp);
        __half2 h23 = __floats2half2_rn(eyA[j] * rcp, eymA[j] * rcp);
        __half2 h45 = __floats2half2_rn(ezA[j] * rcp, ezmA[j] * rcp);
        __half2 h67 = __floats2half2_rn(FOURPI_C * qA[j] * rcp, 0.0f);
        uint4 u;
        u.x = *(unsigned int*)&h01;
        u.y = *(unsigned int*)&h23;
        u.z = *(unsigned int*)&h45;
        u.w = *(unsigned int*)&h67;
        coef[g4 + j] = u;
        ph[j] = __half22float2(h67).x;
    }
    *reinterpret_cast<float4*>(phi1 + g4) = make_float4(ph[0], ph[1], ph[2], ph[3]);
}

// ---------------- fused 2-step Jacobi, prefetched (T14, verified round-6) ---
#define TY 8
#define TZ 32
#define RY (TY + 2)    // 10
#define RZ (TZ + 2)    // 34
#define PYD (TY + 4)   // 12
#define PZD (TZ + 4)   // 36
#define SEG 16         // 2048 blocks = 8/CU

__global__ __launch_bounds__(256)
void jacobi_f2p(const uint4* __restrict__ coef,
                const float* __restrict__ pin,
                float* __restrict__ pout)
{
    int bid = blockIdx.x;                 // 2048 blocks
    int xs = bid & 7;
    int zt = (bid >> 3) & 3;
    int yt = (bid >> 5) & 15;
    int b  = bid >> 9;
    int x_lo = xs * SEG, x_hi = x_lo + SEG - 1;
    int y0 = yt * TY, z0 = zt * TZ;

    __shared__ float P[3][PYD * PZD];     // phi_in slices x, x-1, x-2
    __shared__ float S[3][RY * RZ];       // step-1 phi slices

    int tid = threadIdx.x;
    int oy = tid >> 5, oz = tid & 31;

    const uint4* cb = coef + (size_t)b * VOX_;
    const float* pb = pin  + (size_t)b * VOX_;
    float*       ob = pout + (size_t)b * VOX_;

    // ---- static per-thread geometry ----
    int e1_i  = (oy + 1) * RZ + (oz + 1);
    int g1y = y0 + oy, g1z = z0 + oz;
    int e1_off = g1y * 128 + g1z;
    int e1_p0 = (oy + 2) * PZD + (oz + 2);
    bool has2 = (tid < 84);
    int e2_ry = 0, e2_rz = 0;
    if (tid < 34)      { e2_ry = 0;      e2_rz = tid; }
    else if (tid < 68) { e2_ry = RY - 1; e2_rz = tid - 34; }
    else if (tid < 84) { int t2 = tid - 68; e2_ry = 1 + (t2 >> 1); e2_rz = (t2 & 1) * (RZ - 1); }
    int e2_i = e2_ry * RZ + e2_rz;
    int g2y = y0 - 1 + e2_ry, g2z = z0 - 1 + e2_rz;
    bool e2_ok = ((unsigned)g2y < 128u) && ((unsigned)g2z < 128u);
    int e2_off = min(max(g2y, 0), 127) * 128 + min(max(g2z, 0), 127);
    int e2_p0 = (e2_ry + 1) * PZD + (e2_rz + 1);
    int p1_py = tid / PZD, p1_pz = tid - p1_py * PZD;
    int p1y = y0 - 2 + p1_py, p1z = z0 - 2 + p1_pz;
    bool p1_ok = ((unsigned)p1y < 128u) && ((unsigned)p1z < 128u);
    int p1_off = min(max(p1y, 0), 127) * 128 + min(max(p1z, 0), 127);
    int p2i = tid + 256;
    bool hasP2 = (p2i < PYD * PZD);
    int p2_py = p2i / PZD, p2_pz = p2i - p2_py * PZD;
    int p2y = y0 - 2 + p2_py, p2z = z0 - 2 + p2_pz;
    bool p2_ok = hasP2 && ((unsigned)p2y < 128u) && ((unsigned)p2z < 128u);
    int p2_off = min(max(p2y, 0), 127) * 128 + min(max(p2z, 0), 127);

    const float* ps0 = pb + (size_t)min(max(x_lo - 2, 0), 127) * 16384;
    float pfA = ps0[p1_off];
    float pfB = hasP2 ? ps0[p2_off] : 0.0f;
    uint4 cf1 = make_uint4(0u, 0u, 0u, 0u);
    uint4 cf2 = make_uint4(0u, 0u, 0u, 0u);
    uint4 hold = make_uint4(0u, 0u, 0u, 0u);
    uint4 cnew = make_uint4(0u, 0u, 0u, 0u);

    for (int x = x_lo - 2; x <= x_hi + 2; ++x) {
        int s0 = (x + 3) % 3;             // slot(x)
        int s1 = (x + 2) % 3;             // slot(x-1)
        int s2 = (x + 1) % 3;             // slot(x-2)
        bool xin = (x >= 0 && x < 128);

        // ---- W: commit prefetched phi(x) to P[s0] ----
        P[s0][tid] = (xin && p1_ok) ? pfA : 0.0f;
        if (hasP2) P[s0][p2i] = (xin && p2_ok) ? pfB : 0.0f;
        asm volatile("s_waitcnt lgkmcnt(0)" ::: "memory");
        __builtin_amdgcn_s_barrier();

        // ---- I: issue phi(x+1) prefetch (consumed next W) ----
        if (x < x_hi + 2) {
            const float* ps = pb + (size_t)min(max(x + 1, 0), 127) * 16384;
            pfA = ps[p1_off];
            if (hasP2) pfB = ps[p2_off];
        }

        // ---- B: compute S1(x-1) from coef regs + P ----
        if (x >= x_lo) {
            int k = x - 1;
            bool kin = ((unsigned)k < 128u);
            {
                float v = 0.0f;
                if (kin) {
                    const __half2* h = reinterpret_cast<const __half2*>(&cf1);
                    float2 a01 = __half22float2(h[0]);
                    float2 a23 = __half22float2(h[1]);
                    float2 a45 = __half22float2(h[2]);
                    float2 a67 = __half22float2(h[3]);
                    v = a01.x * P[s0][e1_p0]
                      + a01.y * P[s2][e1_p0]
                      + a23.x * P[s1][e1_p0 + PZD]
                      + a23.y * P[s1][e1_p0 - PZD]
                      + a45.x * P[s1][e1_p0 + 1]
                      + a45.y * P[s1][e1_p0 - 1]
                      + a67.x;
                }
                S[s1][e1_i] = v;
                cnew = cf1;
            }
            if (has2) {
                float v = 0.0f;
                if (kin && e2_ok) {
                    const __half2* h = reinterpret_cast<const __half2*>(&cf2);
                    float2 a01 = __half22float2(h[0]);
                    float2 a23 = __half22float2(h[1]);
                    float2 a45 = __half22float2(h[2]);
                    float2 a67 = __half22float2(h[3]);
                    v = a01.x * P[s0][e2_p0]
                      + a01.y * P[s2][e2_p0]
                      + a23.x * P[s1][e2_p0 + PZD]
                      + a23.y * P[s1][e2_p0 - PZD]
                      + a45.x * P[s1][e2_p0 + 1]
                      + a45.y * P[s1][e2_p0 - 1]
                      + a67.x;
                }
                S[s1][e2_i] = v;
            }
        }
        if (x >= x_lo - 1 && x <= x_hi + 1) {
            const uint4* cs = cb + (size_t)min(max(x, 0), 127) * 16384;
            cf1 = cs[e1_off];
            if (has2) cf2 = cs[e2_off];
        }
        asm volatile("s_waitcnt lgkmcnt(0)" ::: "memory");
        __builtin_amdgcn_s_barrier();

        // ---- C: output xo = x-2 from reg coef + S ----
        int xo = x - 2;
        if (xo >= x_lo) {
            const __half2* h = reinterpret_cast<const __half2*>(&hold);
            float2 a01 = __half22float2(h[0]);
            float2 a23 = __half22float2(h[1]);
            float2 a45 = __half22float2(h[2]);
            float2 a67 = __half22float2(h[3]);
            int j0 = e1_i;
            float out = a01.x * S[s1][j0]
                      + a01.y * S[s0][j0]
                      + a23.x * S[s2][j0 + RZ]
                      + a23.y * S[s2][j0 - RZ]
                      + a45.x * S[s2][j0 + 1]
                      + a45.y * S[s2][j0 - 1]
                      + a67.x;
            ob[(size_t)xo * 16384 + e1_off] = out;
        }
        hold = cnew;
    }
}

// ---------------- Jacobi sweep v3: 4 z-voxels/thread, fp16 coefs (verified) -
__global__ void jacobi_v3(const uint4* __restrict__ coef,
                          const float* __restrict__ pin,
                          float* __restrict__ pout)
{
    int tid = blockIdx.x * blockDim.x + threadIdx.x;   // 0 .. B*VOX/4-1
    size_t g4 = (size_t)tid * 4;
    int z4 = (int)(g4 & 127);          // 0,4,...,124
    int y  = (int)((g4 >> 7) & 127);
    int x  = (int)((g4 >> 14) & 127);

    float4 pcv = *reinterpret_cast<const float4*>(pin + g4);
    float4 z4v = make_float4(0.f, 0.f, 0.f, 0.f);
    float4 pxpv = (x < 127) ? *reinterpret_cast<const float4*>(pin + g4 + 16384) : z4v;
    float4 pxmv = (x > 0)   ? *reinterpret_cast<const float4*>(pin + g4 - 16384) : z4v;
    float4 pypv = (y < 127) ? *reinterpret_cast<const float4*>(pin + g4 + 128)   : z4v;
    float4 pymv = (y > 0)   ? *reinterpret_cast<const float4*>(pin + g4 - 128)   : z4v;
    float zpE = (z4 < 124) ? pin[g4 + 4] : 0.0f;
    float zmE = (z4 > 0)   ? pin[g4 - 1] : 0.0f;

    float pxp[4] = {pxpv.x, pxpv.y, pxpv.z, pxpv.w};
    float pxm[4] = {pxmv.x, pxmv.y, pxmv.z, pxmv.w};
    float pyp[4] = {pypv.x, pypv.y, pypv.z, pypv.w};
    float pym[4] = {pymv.x, pymv.y, pymv.z, pymv.w};
    float pzp[4] = {pcv.y, pcv.z, pcv.w, zpE};
    float pzm[4] = {zmE, pcv.x, pcv.y, pcv.z};

    float out[4];
#pragma unroll
    for (int j = 0; j < 4; ++j) {
        uint4 cu = coef[g4 + j];
        const __half2* h = reinterpret_cast<const __half2*>(&cu);
        float2 a01 = __half22float2(h[0]);
        float2 a23 = __half22float2(h[1]);
        float2 a45 = __half22float2(h[2]);
        float2 a67 = __half22float2(h[3]);
        out[j] = a01.x * pxp[j] + a01.y * pxm[j]
               + a23.x * pyp[j] + a23.y * pym[j]
               + a45.x * pzp[j] + a45.y * pzm[j]
               + a67.x;
    }
    *reinterpret_cast<float4*>(pout + g4) = make_float4(out[0], out[1], out[2], out[3]);
}

// ---------------- Jacobi sweep v2 (fallback path, verified) ----------------
__global__ void jacobi_v2(const float* __restrict__ eps,
                          const float* __restrict__ q,
                          const float* __restrict__ pin,
                          float* __restrict__ pout)
{
    int bxy = blockIdx.x;
    int b = bxy >> 14;
    int x = (bxy >> 7) & 127;
    int y = bxy & 127;
    int z = threadIdx.x;

    size_t sp = ((size_t)x * 128 + y) * 128 + z;
    size_t g  = (size_t)b * (size_t)VOX_ + sp;
    const float* E = eps + (size_t)b * 4 * (size_t)VOX_;

    float ex = E[sp];
    float ey = E[sp + (size_t)VOX_];
    float ez = E[sp + (size_t)VOX_ * 2];
    float ek = E[sp + (size_t)VOX_ * 3];
    float exm = (x > 0) ? E[sp - 16384]                 : EPS_OUT_C;
    float eym = (y > 0) ? E[sp + (size_t)VOX_ - 128]    : EPS_OUT_C;
    float ezm = (z > 0) ? E[sp + (size_t)VOX_ * 2 - 1]  : EPS_OUT_C;

    float lam = (ek - EPS_IN_C) / (EPS_OUT_C - EPS_IN_C);
    lam = fminf(fmaxf(lam, 0.0f), 1.0f);
    float denom = ex + exm + ey + eym + ez + ezm + KAPPA02_C * lam;

    float pxp = (x < 127) ? pin[g + 16384] : 0.0f;
    float pxm = (x > 0)   ? pin[g - 16384] : 0.0f;
    float pyp = (y < 127) ? pin[g + 128]   : 0.0f;
    float pym = (y > 0)   ? pin[g - 128]   : 0.0f;
    float pzp = (z < 127) ? pin[g + 1]     : 0.0f;
    float pzm = (z > 0)   ? pin[g - 1]     : 0.0f;

    float num = ex * pxp + exm * pxm + ey * pyp + eym * pym
              + ez * pzp + ezm * pzm + FOURPI_C * q[g];
    pout[g] = num / denom;
}

// ---------------- launch ----------------
extern "C" void kernel_launch(void* const* d_in, const int* in_sizes, int n_in,
                              void* d_out, int out_size, void* d_ws, size_t ws_size,
                              hipStream_t stream)
{
    const float* coords    = (const float*)d_in[0];
    const float* params    = (const float*)d_in[1];
    const int*   num_atoms = (const int*)d_in[2];

    float* q   = (float*)d_out;                       // [B][128^3]
    float* eps = q + (size_t)B_ * VOX_;               // [B][4][128^3]
    float* phi = eps + (size_t)B_ * 4 * VOX_;         // [B][128^3]

    hipMemsetAsync(q, 0, (size_t)B_ * VOX_ * sizeof(float), stream);

    scatter_q_kernel<<<(B_ * N_ + 255) / 256, 256, 0, stream>>>(coords, params, num_atoms, q);
    eps_gather_v2<<<B_ * 4096, 512, 0, stream>>>(coords, params, num_atoms, eps);

    size_t coefBytes = (size_t)B_ * VOX_ * sizeof(uint4);              // 134 MB
    size_t need = coefBytes + (size_t)B_ * VOX_ * sizeof(float);       // +33.5 MB

    if (ws_size >= need) {
        uint4* coefA = (uint4*)d_ws;
        float* tmp   = (float*)((char*)d_ws + coefBytes);
        // sweep 1 folded into coef_pack4 (phi_0 == 0): phi1 -> phi
        coef_pack4<<<(int)(B_ * VOX_ / 4 / 256), 256, 0, stream>>>(eps, q, coefA, phi);
        const float* cur = phi;
        for (int it = 1; it <= 9; ++it) {           // 9 fused = sweeps 2..19
            float* dst = (it & 1) ? tmp : phi;      // it=9 (odd) -> tmp
            jacobi_f2p<<<B_ * 16 * 4 * 8, 256, 0, stream>>>(coefA, cur, dst);
            cur = dst;
        }
        // sweep 20: single v3 sweep tmp -> phi (d_out)
        jacobi_v3<<<(int)(B_ * VOX_ / 4 / 256), 256, 0, stream>>>(coefA, cur, phi);
    } else {
        hipMemsetAsync(phi, 0, (size_t)B_ * VOX_ * sizeof(float), stream);
        float* tmp = (float*)d_ws;
        int jb = B_ * 128 * 128;
        const float* cur = phi;
        for (int it = 1; it <= 20; ++it) {
            float* dst = (it & 1) ? tmp : phi;
            jacobi_v2<<<jb, 128, 0, stream>>>(eps, q, cur, dst);
            cur = dst;
        }
    }
}

// Round 8
// 719.417 us; speedup vs baseline: 2.4327x; 1.0022x over previous
//
#include <hip/hip_runtime.h>
#include <hip/hip_fp16.h>
#include <math.h>

// ---------------- problem constants ----------------
static constexpr int   B_    = 4;
static constexpr int   N_    = 4096;
static constexpr int   BOX_  = 128;
static constexpr long long VOX_ = 1LL * BOX_ * BOX_ * BOX_;   // 2097152
static constexpr float EPS_IN_C  = 6.5f;
static constexpr float EPS_OUT_C = 79.0f;
static constexpr float QCONV_C   = 7046.52f;
static constexpr float KAPPA02_C = 0.8486f;
static constexpr float FOURPI_C  = 12.566370614359172f;

// ---------------- trilinear charge scatter (verified) ----------
__global__ void scatter_q_kernel(const float* __restrict__ coords,
                                 const float* __restrict__ params,
                                 const int*   __restrict__ num_atoms,
                                 float* __restrict__ q)
{
    int a = blockIdx.x * blockDim.x + threadIdx.x;
    if (a >= B_ * N_) return;
    int b = a >> 12;
    int n = a & (N_ - 1);
    if (n >= num_atoms[b]) return;

    float cx = coords[3 * a + 0];
    float cy = coords[3 * a + 1];
    float cz = coords[3 * a + 2];
    float chg = params[2 * a + 0] * QCONV_C;

    int ix0 = (int)floorf(cx), iy0 = (int)floorf(cy), iz0 = (int)floorf(cz);
    float fx = cx - (float)ix0, fy = cy - (float)iy0, fz = cz - (float)iz0;
    float wx[2] = {1.0f - fx, fx};
    float wy[2] = {1.0f - fy, fy};
    float wz[2] = {1.0f - fz, fz};

    float* qb = q + (long long)b * VOX_;
#pragma unroll
    for (int dx = 0; dx < 2; ++dx) {
        int ix = ix0 + dx;
        if ((unsigned)ix >= 128u) continue;
#pragma unroll
        for (int dy = 0; dy < 2; ++dy) {
            int iy = iy0 + dy;
            if ((unsigned)iy >= 128u) continue;
#pragma unroll
            for (int dz = 0; dz < 2; ++dz) {
                int iz = iz0 + dz;
                if ((unsigned)iz >= 128u) continue;
                atomicAdd(&qb[((long long)ix * 128 + iy) * 128 + iz],
                          chg * wx[dx] * wy[dy] * wz[dz]);
            }
        }
    }
}

// ---------------- eps gather v3: z-column blocks, scan amortized 16x --------
// One block per (b, tx, ty): scans atoms ONCE with the exact x/y window test
// (c in [t-4, t+12.5) union wrap c<4.5 for t=120; round-7 verified bounds),
// then per z-tile applies the z test in-LDS and runs the verified Phase A/B.
// Candidate SET per tile is identical to round-7; only accumulation order
// differs (already scheduler-nondeterministic via atomicAdd slot order).
#define CAND_CAP 512
#define CHUNK 32

__global__ __launch_bounds__(512)
void eps_gather_v3(const float* __restrict__ coords,
                   const float* __restrict__ params,
                   const int*   __restrict__ num_atoms,
                   float* __restrict__ eps)   // [B][4][128^3]
{
    int bid = blockIdx.x;               // B * 16 * 16 blocks
    int b   = bid >> 8;
    int txi = (bid >> 4) & 15;
    int tyi = bid & 15;
    int tx = txi << 3, ty = tyi << 3;

    __shared__ float sx[CAND_CAP], sy[CAND_CAP], sz[CAND_CAP], sr[CAND_CAP];
    __shared__ float wts[CHUNK][9][8];   // [atom][axis*3+variant][tile pos]
    __shared__ int  fidx[CAND_CAP];      // per-z-tile filtered candidate idx
    __shared__ int  s_cnt, s_fcnt;
    if (threadIdx.x == 0) s_cnt = 0;
    __syncthreads();

    int na = num_atoms[b];
    const float* cb = coords + (size_t)b * N_ * 3;
    const float* pb = params + (size_t)b * N_ * 2;

    // ---- xy scan (once per column) ----
    float lox = (float)tx - 4.0f, hix = (float)tx + 12.5f;
    float loy = (float)ty - 4.0f, hiy = (float)ty + 12.5f;
    bool wx_ = (tx == 120), wy_ = (ty == 120);
    for (int n = threadIdx.x; n < na; n += 512) {
        float cx = cb[3 * n], cy = cb[3 * n + 1], cz = cb[3 * n + 2];
        bool okx = (cx >= lox && cx < hix) || (wx_ && cx < 4.5f);
        bool oky = (cy >= loy && cy < hiy) || (wy_ && cy < 4.5f);
        if (okx && oky) {
            int slot = atomicAdd(&s_cnt, 1);
            if (slot < CAND_CAP) {
                sx[slot] = cx; sy[slot] = cy; sz[slot] = cz;
                sr[slot] = pb[2 * n + 1];
            }
        }
    }
    __syncthreads();
    int cnt = min(s_cnt, CAND_CAP);

    int lz = threadIdx.x & 7;
    int ly = (threadIdx.x >> 3) & 7;
    int lx = threadIdx.x >> 6;

    float* eb = eps + (size_t)b * 4 * VOX_;

    for (int tzi = 0; tzi < 16; ++tzi) {
        int tz = tzi << 3;

        // ---- z filter into fidx ----
        __syncthreads();                 // prior Phase B / fidx reads done
        if (threadIdx.x == 0) s_fcnt = 0;
        __syncthreads();
        {
            float loz = (float)tz - 4.0f, hiz = (float)tz + 12.5f;
            bool wz_ = (tz == 120);
            for (int i = threadIdx.x; i < cnt; i += 512) {
                float cz = sz[i];
                if ((cz >= loz && cz < hiz) || (wz_ && cz < 4.5f)) {
                    int s = atomicAdd(&s_fcnt, 1);
                    fidx[s] = i;
                }
            }
        }
        __syncthreads();
        int fcnt = s_fcnt;

        float r0 = 0.0f, r1 = 0.0f, r2 = 0.0f, r3 = 0.0f;

        for (int k0 = 0; k0 < fcnt; k0 += CHUNK) {
            int nC = min(CHUNK, fcnt - k0);
            __syncthreads();             // protect wts reuse across chunks
            // Phase A: per-atom separable axis weights (72 expf per atom)
            for (int w = threadIdx.x; w < nC * 72; w += 512) {
                int ka  = w / 72;
                int rem = w - ka * 72;
                int vi  = rem >> 3;      // 0..8 = axis*3 + variant
                int pos = rem & 7;
                int axis = vi / 3, var = vi - axis * 3;
                int k = fidx[k0 + ka];
                float c     = (axis == 0) ? sx[k] : (axis == 1) ? sy[k] : sz[k];
                int   torig = (axis == 0) ? tx    : (axis == 1) ? ty    : tz;
                float r = sr[k];
                float sig = (var == 2) ? (r + 1.0f) * 0.5f : (r + 1.4f) * 0.5f;
                float off = (var == 0) ? 0.0f : 0.5f;
                float inv2s2 = 1.0f / (2.0f * sig * sig);
                int i = torig + pos;
                int base = (int)floorf(c - off) - 4;    // window [base, base+8]
                float wv = 0.0f;
                if ((unsigned)(i - base) <= 8u) {
                    float d = (float)i + off - c;
                    wv = expf(-d * d * inv2s2);
                } else if ((unsigned)(i - 128 - base) <= 8u) {   // JAX wrap
                    float d = (float)(i - 128) + off - c;
                    wv = expf(-d * d * inv2s2);
                }
                wts[ka][vi][pos] = wv;
            }
            __syncthreads();
            // Phase B: accumulate channels from separable products
            for (int ka = 0; ka < nC; ++ka) {
                float xE0 = wts[ka][0][lx], xE5 = wts[ka][1][lx], xI5 = wts[ka][2][lx];
                float yE0 = wts[ka][3][ly], yE5 = wts[ka][4][ly], yI5 = wts[ka][5][ly];
                float zE0 = wts[ka][6][lz], zE5 = wts[ka][7][lz], zI5 = wts[ka][8][lz];
                r0 += xE5 * yE0 * zE0;     // c0: off (.5,0,0)  sigE
                r1 += xE0 * yE5 * zE0;     // c1: off (0,.5,0)  sigE
                r2 += xE0 * yE0 * zE5;     // c2: off (0,0,.5)  sigE
                r3 += xI5 * yI5 * zI5;     // c3: off (.5,.5,.5) sigI
            }
        }

        int ix = tx + lx, iy = ty + ly, iz = tz + lz;
        size_t sp = ((size_t)ix * 128 + iy) * 128 + iz;
        eb[sp]                    = EPS_OUT_C + (EPS_IN_C - EPS_OUT_C) * fminf(fmaxf(r0, 0.0f), 1.0f);
        eb[sp + (size_t)VOX_]     = EPS_OUT_C + (EPS_IN_C - EPS_OUT_C) * fminf(fmaxf(r1, 0.0f), 1.0f);
        eb[sp + (size_t)VOX_ * 2] = EPS_OUT_C + (EPS_IN_C - EPS_OUT_C) * fminf(fmaxf(r2, 0.0f), 1.0f);
        eb[sp + (size_t)VOX_ * 3] = EPS_OUT_C + (EPS_IN_C - EPS_OUT_C) * fminf(fmaxf(r3, 0.0f), 1.0f);
    }
}

// ---------------- coefficient pack v4: 4 z-voxels/thread, vectorized --------
// Folds Jacobi sweep 1 (phi_0 == 0): phi1 = float(half(4*pi*q*rcp)).
__global__ void coef_pack4(const float* __restrict__ eps,
                           const float* __restrict__ q,
                           uint4* __restrict__ coef,
                           float* __restrict__ phi1)
{
    int tid = blockIdx.x * blockDim.x + threadIdx.x;   // 0 .. B*VOX/4-1
    size_t g4 = (size_t)tid * 4;
    int b  = (int)(g4 >> 21);
    size_t sp = g4 & (size_t)(VOX_ - 1);
    int x  = (int)(sp >> 14);
    int y  = (int)((sp >> 7) & 127);
    int z4 = (int)(sp & 127);          // 0,4,...,124

    const float* E = eps + (size_t)b * 4 * (size_t)VOX_;
    float4 ex4 = *reinterpret_cast<const float4*>(E + sp);
    float4 ey4 = *reinterpret_cast<const float4*>(E + sp + (size_t)VOX_);
    float4 ez4 = *reinterpret_cast<const float4*>(E + sp + (size_t)VOX_ * 2);
    float4 ek4 = *reinterpret_cast<const float4*>(E + sp + (size_t)VOX_ * 3);
    float4 eo  = make_float4(EPS_OUT_C, EPS_OUT_C, EPS_OUT_C, EPS_OUT_C);
    float4 exm4 = (x > 0) ? *reinterpret_cast<const float4*>(E + sp - 16384) : eo;
    float4 eym4 = (y > 0) ? *reinterpret_cast<const float4*>(E + sp + (size_t)VOX_ - 128) : eo;
    float ezm0  = (z4 > 0) ? E[sp + (size_t)VOX_ * 2 - 1] : EPS_OUT_C;
    float4 q4  = *reinterpret_cast<const float4*>(q + g4);

    float exA[4]  = {ex4.x, ex4.y, ex4.z, ex4.w};
    float eyA[4]  = {ey4.x, ey4.y, ey4.z, ey4.w};
    float ezA[4]  = {ez4.x, ez4.y, ez4.z, ez4.w};
    float ekA[4]  = {ek4.x, ek4.y, ek4.z, ek4.w};
    float exmA[4] = {exm4.x, exm4.y, exm4.z, exm4.w};
    float eymA[4] = {eym4.x, eym4.y, eym4.z, eym4.w};
    float ezmA[4] = {ezm0, ez4.x, ez4.y, ez4.z};
    float qA[4]   = {q4.x, q4.y, q4.z, q4.w};

    float ph[4];
#pragma unroll
    for (int j = 0; j < 4; ++j) {
        float lam = (ekA[j] - EPS_IN_C) / (EPS_OUT_C - EPS_IN_C);
        lam = fminf(fmaxf(lam, 0.0f), 1.0f);
        float denom = exA[j] + exmA[j] + eyA[j] + eymA[j] + ezA[j] + ezmA[j]
                    + KAPPA02_C * lam;
        float rcp = 1.0f / denom;

        __half2 h01 = __floats2half2_rn(exA[j] * rcp, exmA[j] * rcp);
        __half2 h23 = __floats2half2_rn(eyA[j] * rcp, eymA[j] * rcp);
        __half2 h45 = __floats2half2_rn(ezA[j] * rcp, ezmA[j] * rcp);
        __half2 h67 = __floats2half2_rn(FOURPI_C * qA[j] * rcp, 0.0f);
        uint4 u;
        u.x = *(unsigned int*)&h01;
        u.y = *(unsigned int*)&h23;
        u.z = *(unsigned int*)&h45;
        u.w = *(unsigned int*)&h67;
        coef[g4 + j] = u;
        ph[j] = __half22float2(h67).x;
    }
    *reinterpret_cast<float4*>(phi1 + g4) = make_float4(ph[0], ph[1], ph[2], ph[3]);
}

// ---------------- fused 2-step Jacobi, prefetched (T14, verified round-6) ---
#define TY 8
#define TZ 32
#define RY (TY + 2)    // 10
#define RZ (TZ + 2)    // 34
#define PYD (TY + 4)   // 12
#define PZD (TZ + 4)   // 36
#define SEG 16         // 2048 blocks = 8/CU

__global__ __launch_bounds__(256)
void jacobi_f2p(const uint4* __restrict__ coef,
                const float* __restrict__ pin,
                float* __restrict__ pout)
{
    int bid = blockIdx.x;                 // 2048 blocks
    int xs = bid & 7;
    int zt = (bid >> 3) & 3;
    int yt = (bid >> 5) & 15;
    int b  = bid >> 9;
    int x_lo = xs * SEG, x_hi = x_lo + SEG - 1;
    int y0 = yt * TY, z0 = zt * TZ;

    __shared__ float P[3][PYD * PZD];     // phi_in slices x, x-1, x-2
    __shared__ float S[3][RY * RZ];       // step-1 phi slices

    int tid = threadIdx.x;
    int oy = tid >> 5, oz = tid & 31;

    const uint4* cb = coef + (size_t)b * VOX_;
    const float* pb = pin  + (size_t)b * VOX_;
    float*       ob = pout + (size_t)b * VOX_;

    // ---- static per-thread geometry ----
    int e1_i  = (oy + 1) * RZ + (oz + 1);
    int g1y = y0 + oy, g1z = z0 + oz;
    int e1_off = g1y * 128 + g1z;
    int e1_p0 = (oy + 2) * PZD + (oz + 2);
    bool has2 = (tid < 84);
    int e2_ry = 0, e2_rz = 0;
    if (tid < 34)      { e2_ry = 0;      e2_rz = tid; }
    else if (tid < 68) { e2_ry = RY - 1; e2_rz = tid - 34; }
    else if (tid < 84) { int t2 = tid - 68; e2_ry = 1 + (t2 >> 1); e2_rz = (t2 & 1) * (RZ - 1); }
    int e2_i = e2_ry * RZ + e2_rz;
    int g2y = y0 - 1 + e2_ry, g2z = z0 - 1 + e2_rz;
    bool e2_ok = ((unsigned)g2y < 128u) && ((unsigned)g2z < 128u);
    int e2_off = min(max(g2y, 0), 127) * 128 + min(max(g2z, 0), 127);
    int e2_p0 = (e2_ry + 1) * PZD + (e2_rz + 1);
    int p1_py = tid / PZD, p1_pz = tid - p1_py * PZD;
    int p1y = y0 - 2 + p1_py, p1z = z0 - 2 + p1_pz;
    bool p1_ok = ((unsigned)p1y < 128u) && ((unsigned)p1z < 128u);
    int p1_off = min(max(p1y, 0), 127) * 128 + min(max(p1z, 0), 127);
    int p2i = tid + 256;
    bool hasP2 = (p2i < PYD * PZD);
    int p2_py = p2i / PZD, p2_pz = p2i - p2_py * PZD;
    int p2y = y0 - 2 + p2_py, p2z = z0 - 2 + p2_pz;
    bool p2_ok = hasP2 && ((unsigned)p2y < 128u) && ((unsigned)p2z < 128u);
    int p2_off = min(max(p2y, 0), 127) * 128 + min(max(p2z, 0), 127);

    const float* ps0 = pb + (size_t)min(max(x_lo - 2, 0), 127) * 16384;
    float pfA = ps0[p1_off];
    float pfB = hasP2 ? ps0[p2_off] : 0.0f;
    uint4 cf1 = make_uint4(0u, 0u, 0u, 0u);
    uint4 cf2 = make_uint4(0u, 0u, 0u, 0u);
    uint4 hold = make_uint4(0u, 0u, 0u, 0u);
    uint4 cnew = make_uint4(0u, 0u, 0u, 0u);

    for (int x = x_lo - 2; x <= x_hi + 2; ++x) {
        int s0 = (x + 3) % 3;             // slot(x)
        int s1 = (x + 2) % 3;             // slot(x-1)
        int s2 = (x + 1) % 3;             // slot(x-2)
        bool xin = (x >= 0 && x < 128);

        // ---- W: commit prefetched phi(x) to P[s0] ----
        P[s0][tid] = (xin && p1_ok) ? pfA : 0.0f;
        if (hasP2) P[s0][p2i] = (xin && p2_ok) ? pfB : 0.0f;
        asm volatile("s_waitcnt lgkmcnt(0)" ::: "memory");
        __builtin_amdgcn_s_barrier();

        // ---- I: issue phi(x+1) prefetch (consumed next W) ----
        if (x < x_hi + 2) {
            const float* ps = pb + (size_t)min(max(x + 1, 0), 127) * 16384;
            pfA = ps[p1_off];
            if (hasP2) pfB = ps[p2_off];
        }

        // ---- B: compute S1(x-1) from coef regs + P ----
        if (x >= x_lo) {
            int k = x - 1;
            bool kin = ((unsigned)k < 128u);
            {
                float v = 0.0f;
                if (kin) {
                    const __half2* h = reinterpret_cast<const __half2*>(&cf1);
                    float2 a01 = __half22float2(h[0]);
                    float2 a23 = __half22float2(h[1]);
                    float2 a45 = __half22float2(h[2]);
                    float2 a67 = __half22float2(h[3]);
                    v = a01.x * P[s0][e1_p0]
                      + a01.y * P[s2][e1_p0]
                      + a23.x * P[s1][e1_p0 + PZD]
                      + a23.y * P[s1][e1_p0 - PZD]
                      + a45.x * P[s1][e1_p0 + 1]
                      + a45.y * P[s1][e1_p0 - 1]
                      + a67.x;
                }
                S[s1][e1_i] = v;
                cnew = cf1;
            }
            if (has2) {
                float v = 0.0f;
                if (kin && e2_ok) {
                    const __half2* h = reinterpret_cast<const __half2*>(&cf2);
                    float2 a01 = __half22float2(h[0]);
                    float2 a23 = __half22float2(h[1]);
                    float2 a45 = __half22float2(h[2]);
                    float2 a67 = __half22float2(h[3]);
                    v = a01.x * P[s0][e2_p0]
                      + a01.y * P[s2][e2_p0]
                      + a23.x * P[s1][e2_p0 + PZD]
                      + a23.y * P[s1][e2_p0 - PZD]
                      + a45.x * P[s1][e2_p0 + 1]
                      + a45.y * P[s1][e2_p0 - 1]
                      + a67.x;
                }
                S[s1][e2_i] = v;
            }
        }
        if (x >= x_lo - 1 && x <= x_hi + 1) {
            const uint4* cs = cb + (size_t)min(max(x, 0), 127) * 16384;
            cf1 = cs[e1_off];
            if (has2) cf2 = cs[e2_off];
        }
        asm volatile("s_waitcnt lgkmcnt(0)" ::: "memory");
        __builtin_amdgcn_s_barrier();

        // ---- C: output xo = x-2 from reg coef + S ----
        int xo = x - 2;
        if (xo >= x_lo) {
            const __half2* h = reinterpret_cast<const __half2*>(&hold);
            float2 a01 = __half22float2(h[0]);
            float2 a23 = __half22float2(h[1]);
            float2 a45 = __half22float2(h[2]);
            float2 a67 = __half22float2(h[3]);
            int j0 = e1_i;
            float out = a01.x * S[s1][j0]
                      + a01.y * S[s0][j0]
                      + a23.x * S[s2][j0 + RZ]
                      + a23.y * S[s2][j0 - RZ]
                      + a45.x * S[s2][j0 + 1]
                      + a45.y * S[s2][j0 - 1]
                      + a67.x;
            ob[(size_t)xo * 16384 + e1_off] = out;
        }
        hold = cnew;
    }
}

// ---------------- Jacobi sweep v3: 4 z-voxels/thread, fp16 coefs (verified) -
__global__ void jacobi_v3(const uint4* __restrict__ coef,
                          const float* __restrict__ pin,
                          float* __restrict__ pout)
{
    int tid = blockIdx.x * blockDim.x + threadIdx.x;   // 0 .. B*VOX/4-1
    size_t g4 = (size_t)tid * 4;
    int z4 = (int)(g4 & 127);          // 0,4,...,124
    int y  = (int)((g4 >> 7) & 127);
    int x  = (int)((g4 >> 14) & 127);

    float4 pcv = *reinterpret_cast<const float4*>(pin + g4);
    float4 z4v = make_float4(0.f, 0.f, 0.f, 0.f);
    float4 pxpv = (x < 127) ? *reinterpret_cast<const float4*>(pin + g4 + 16384) : z4v;
    float4 pxmv = (x > 0)   ? *reinterpret_cast<const float4*>(pin + g4 - 16384) : z4v;
    float4 pypv = (y < 127) ? *reinterpret_cast<const float4*>(pin + g4 + 128)   : z4v;
    float4 pymv = (y > 0)   ? *reinterpret_cast<const float4*>(pin + g4 - 128)   : z4v;
    float zpE = (z4 < 124) ? pin[g4 + 4] : 0.0f;
    float zmE = (z4 > 0)   ? pin[g4 - 1] : 0.0f;

    float pxp[4] = {pxpv.x, pxpv.y, pxpv.z, pxpv.w};
    float pxm[4] = {pxmv.x, pxmv.y, pxmv.z, pxmv.w};
    float pyp[4] = {pypv.x, pypv.y, pypv.z, pypv.w};
    float pym[4] = {pymv.x, pymv.y, pymv.z, pymv.w};
    float pzp[4] = {pcv.y, pcv.z, pcv.w, zpE};
    float pzm[4] = {zmE, pcv.x, pcv.y, pcv.z};

    float out[4];
#pragma unroll
    for (int j = 0; j < 4; ++j) {
        uint4 cu = coef[g4 + j];
        const __half2* h = reinterpret_cast<const __half2*>(&cu);
        float2 a01 = __half22float2(h[0]);
        float2 a23 = __half22float2(h[1]);
        float2 a45 = __half22float2(h[2]);
        float2 a67 = __half22float2(h[3]);
        out[j] = a01.x * pxp[j] + a01.y * pxm[j]
               + a23.x * pyp[j] + a23.y * pym[j]
               + a45.x * pzp[j] + a45.y * pzm[j]
               + a67.x;
    }
    *reinterpret_cast<float4*>(pout + g4) = make_float4(out[0], out[1], out[2], out[3]);
}

// ---------------- Jacobi sweep v2 (fallback path, verified) ----------------
__global__ void jacobi_v2(const float* __restrict__ eps,
                          const float* __restrict__ q,
                          const float* __restrict__ pin,
                          float* __restrict__ pout)
{
    int bxy = blockIdx.x;
    int b = bxy >> 14;
    int x = (bxy >> 7) & 127;
    int y = bxy & 127;
    int z = threadIdx.x;

    size_t sp = ((size_t)x * 128 + y) * 128 + z;
    size_t g  = (size_t)b * (size_t)VOX_ + sp;
    const float* E = eps + (size_t)b * 4 * (size_t)VOX_;

    float ex = E[sp];
    float ey = E[sp + (size_t)VOX_];
    float ez = E[sp + (size_t)VOX_ * 2];
    float ek = E[sp + (size_t)VOX_ * 3];
    float exm = (x > 0) ? E[sp - 16384]                 : EPS_OUT_C;
    float eym = (y > 0) ? E[sp + (size_t)VOX_ - 128]    : EPS_OUT_C;
    float ezm = (z > 0) ? E[sp + (size_t)VOX_ * 2 - 1]  : EPS_OUT_C;

    float lam = (ek - EPS_IN_C) / (EPS_OUT_C - EPS_IN_C);
    lam = fminf(fmaxf(lam, 0.0f), 1.0f);
    float denom = ex + exm + ey + eym + ez + ezm + KAPPA02_C * lam;

    float pxp = (x < 127) ? pin[g + 16384] : 0.0f;
    float pxm = (x > 0)   ? pin[g - 16384] : 0.0f;
    float pyp = (y < 127) ? pin[g + 128]   : 0.0f;
    float pym = (y > 0)   ? pin[g - 128]   : 0.0f;
    float pzp = (z < 127) ? pin[g + 1]     : 0.0f;
    float pzm = (z > 0)   ? pin[g - 1]     : 0.0f;

    float num = ex * pxp + exm * pxm + ey * pyp + eym * pym
              + ez * pzp + ezm * pzm + FOURPI_C * q[g];
    pout[g] = num / denom;
}

// ---------------- launch ----------------
extern "C" void kernel_launch(void* const* d_in, const int* in_sizes, int n_in,
                              void* d_out, int out_size, void* d_ws, size_t ws_size,
                              hipStream_t stream)
{
    const float* coords    = (const float*)d_in[0];
    const float* params    = (const float*)d_in[1];
    const int*   num_atoms = (const int*)d_in[2];

    float* q   = (float*)d_out;                       // [B][128^3]
    float* eps = q + (size_t)B_ * VOX_;               // [B][4][128^3]
    float* phi = eps + (size_t)B_ * 4 * VOX_;         // [B][128^3]

    hipMemsetAsync(q, 0, (size_t)B_ * VOX_ * sizeof(float), stream);

    scatter_q_kernel<<<(B_ * N_ + 255) / 256, 256, 0, stream>>>(coords, params, num_atoms, q);
    eps_gather_v3<<<B_ * 16 * 16, 512, 0, stream>>>(coords, params, num_atoms, eps);

    size_t coefBytes = (size_t)B_ * VOX_ * sizeof(uint4);              // 134 MB
    size_t need = coefBytes + (size_t)B_ * VOX_ * sizeof(float);       // +33.5 MB

    if (ws_size >= need) {
        uint4* coefA = (uint4*)d_ws;
        float* tmp   = (float*)((char*)d_ws + coefBytes);
        // sweep 1 folded into coef_pack4 (phi_0 == 0): phi1 -> phi
        coef_pack4<<<(int)(B_ * VOX_ / 4 / 256), 256, 0, stream>>>(eps, q, coefA, phi);
        const float* cur = phi;
        for (int it = 1; it <= 9; ++it) {           // 9 fused = sweeps 2..19
            float* dst = (it & 1) ? tmp : phi;      // it=9 (odd) -> tmp
            jacobi_f2p<<<B_ * 16 * 4 * 8, 256, 0, stream>>>(coefA, cur, dst);
            cur = dst;
        }
        // sweep 20: single v3 sweep tmp -> phi (d_out)
        jacobi_v3<<<(int)(B_ * VOX_ / 4 / 256), 256, 0, stream>>>(coefA, cur, phi);
    } else {
        hipMemsetAsync(phi, 0, (size_t)B_ * VOX_ * sizeof(float), stream);
        float* tmp = (float*)d_ws;
        int jb = B_ * 128 * 128;
        const float* cur = phi;
        for (int it = 1; it <= 20; ++it) {
            float* dst = (it & 1) ? tmp : phi;
            jacobi_v2<<<jb, 128, 0, stream>>>(eps, q, cur, dst);
            cur = dst;
        }
    }
}